// Round 6
// baseline (757.546 us; speedup 1.0000x reference)
//
#include <hip/hip_runtime.h>
#include <math.h>

#define BB 4
#define TT 12
#define NN 2000
#define CC 8
#define HH 64
#define EE 32000
#define NHEADS 8
#define HD 8
#define HORZ 12
#define BT (BB*TT)        // 48
#define RR (BT*NN)        // 96000 rows of H=64

using bf16x8 = __attribute__((ext_vector_type(8))) __bf16;
using f16x8  = __attribute__((ext_vector_type(8))) _Float16;
using f16x4  = __attribute__((ext_vector_type(4))) _Float16;
using f32x4  = __attribute__((ext_vector_type(4))) float;

__device__ __forceinline__ float sigmoidf_(float x){ return 1.0f/(1.0f+__expf(-x)); }
__device__ __forceinline__ float siluf_(float x){ return x/(1.0f+__expf(-x)); }

// ================= CSR build (edges sorted by tgt) =================
__global__ void k_hist(const int* __restrict__ eidx, int* __restrict__ cnt) {
    int e = blockIdx.x*blockDim.x + threadIdx.x;
    if (e < EE) atomicAdd(&cnt[eidx[EE + e]], 1);
}

__global__ __launch_bounds__(256) void k_scan(const int* __restrict__ cnt,
                                              int* __restrict__ ofs_work) {
    __shared__ int part[256];
    int tid = threadIdx.x;
    int local[8]; int s = 0;
    #pragma unroll
    for (int k = 0; k < 8; ++k) {
        int idx = tid*8 + k;
        int v = (idx < NN) ? cnt[idx] : 0;
        local[k] = s; s += v;
    }
    part[tid] = s; __syncthreads();
    for (int off = 1; off < 256; off <<= 1) {
        int v = part[tid];
        int u = (tid >= off) ? part[tid-off] : 0;
        __syncthreads();
        part[tid] = v + u;
        __syncthreads();
    }
    int excl = part[tid] - s;
    #pragma unroll
    for (int k = 0; k < 8; ++k) {
        int idx = tid*8 + k;
        if (idx < NN) ofs_work[idx] = excl + local[k];
    }
}

__global__ void k_scatter(const int* __restrict__ eidx, int* __restrict__ ofs_work,
                          int* __restrict__ ssrc, int* __restrict__ stgt) {
    int e = blockIdx.x*blockDim.x + threadIdx.x;
    if (e >= EE) return;
    int t = eidx[EE + e];
    int pos = atomicAdd(&ofs_work[t], 1);
    ssrc[pos] = eidx[e];
    stgt[pos] = t;
}

// ========== W2 -> bf16, transposed to B-fragment-friendly [n][k] ==========
__global__ void k_w2prep(const float* __restrict__ w2, __bf16* __restrict__ w2t) {
    int i = blockIdx.x*blockDim.x + threadIdx.x;  // 2048 = 64 n * 32 k
    if (i >= 2048) return;
    int n = i >> 5, k = i & 31;
    w2t[i] = (__bf16)w2[k*64 + n];
}

// ---------------- up-projection + fused sp1 msg-layer-1 precompute -------
// 4 rows/wave; pre via readlane broadcasts of the register-resident h values.
__global__ void k_up(const float* __restrict__ x, const float* __restrict__ w,
                     const float* __restrict__ b, const float* __restrict__ w1msg,
                     float* __restrict__ h, _Float16* __restrict__ preB) {
    int gid = blockIdx.x*blockDim.x + threadIdx.x;
    int wv_ = gid >> 6; int j = gid & 63;
    int r0 = wv_*4;
    if (r0 >= RR) return;
    r0 = __builtin_amdgcn_readfirstlane(r0);
    const float* xr = x + (size_t)r0*CC;
    float bj = b[j];
    float a0=bj,a1=bj,a2=bj,a3=bj;
    #pragma unroll
    for (int c = 0; c < CC; ++c) {
        float wc = w[c*HH + j];
        a0 += xr[c]*wc; a1 += xr[CC+c]*wc; a2 += xr[2*CC+c]*wc; a3 += xr[3*CC+c]*wc;
    }
    a0 = fmaxf(a0, 0.f); a1 = fmaxf(a1, 0.f); a2 = fmaxf(a2, 0.f); a3 = fmaxf(a3, 0.f);
    h[(size_t)r0*HH + j]        = a0;
    h[(size_t)r0*HH + HH + j]   = a1;
    h[(size_t)r0*HH + 2*HH + j] = a2;
    h[(size_t)r0*HH + 3*HH + j] = a3;

    // pre = h @ [W1_top | W1_bot]  (factored first msg-MLP layer)
    int base = (j < 32) ? j : (2048 + j - 32);
    float p0=0.f,p1=0.f,p2=0.f,p3=0.f;
    #pragma unroll
    for (int c = 0; c < 64; ++c) {
        float w1c = w1msg[c*32 + base];
        p0 += __shfl(a0, c)*w1c; p1 += __shfl(a1, c)*w1c;
        p2 += __shfl(a2, c)*w1c; p3 += __shfl(a3, c)*w1c;
    }
    preB[(size_t)r0*HH + j]        = (_Float16)p0;
    preB[(size_t)r0*HH + HH + j]   = (_Float16)p1;
    preB[(size_t)r0*HH + 2*HH + j] = (_Float16)p2;
    preB[(size_t)r0*HH + 3*HH + j] = (_Float16)p3;
}

// ========== message MLP + gate + indicator-MFMA segmented aggregation =====
// 256-thread blocks: 4 waves, same edge window, bt = btg*4 + wave.
__global__ __launch_bounds__(256) void k_msg(
    const _Float16* __restrict__ preB, const int* __restrict__ ssrc,
    const int* __restrict__ stgt,
    const float* __restrict__ b1,
    const __bf16* __restrict__ w2t, const float* __restrict__ b2,
    const float* __restrict__ gw, const float* __restrict__ gb,
    float* __restrict__ agg)
{
    const int EB = EE/64; // 500
    int eb  = blockIdx.x % EB;
    int btg = blockIdx.x / EB;        // 0..11
    int wid = threadIdx.x >> 6;
    int bt  = btg*4 + wid;
    int t   = threadIdx.x & 63;
    int l15 = t & 15, quad = t >> 4;

    union __align__(16) SM {
        __bf16   ab[64][40];     // layer-2 A-frag staging (stride 40 -> conflict-free b128)
        _Float16 bs[8][64][8];   // agg B-frag staging: [chunk*4+ni][lane][j]
    };
    __shared__ SM sm[4];
    __shared__ int segTgt4[4][64];

    int e0 = eb*64;
    int my_src = ssrc[e0 + t];
    int my_tgt = stgt[e0 + t];

    // ---- segment ids within window (edges sorted by tgt) ----
    int prevt = __shfl(my_tgt, (t + 63) & 63);
    bool bnd = (t == 0) || (prevt != my_tgt);
    unsigned long long bm = __ballot(bnd);
    int seg = __builtin_amdgcn_mbcnt_hi((unsigned)(bm >> 32),
              __builtin_amdgcn_mbcnt_lo((unsigned)bm, 0u));
    int nseg = __popcll(bm);
    if (bnd) segTgt4[wid][seg] = my_tgt;

    // ---- direct register gather + factored layer 1 (lane t = edge e0+t) ----
    const _Float16* basep = preB + (size_t)bt*NN*HH;
    const _Float16* rT = basep + (size_t)my_tgt*HH;        // xi part: cols 0..31
    const _Float16* rS = basep + (size_t)my_src*HH + 32;   // xj part: cols 32..63
    f16x8 xi[4], xj[4];
    #pragma unroll
    for (int g4 = 0; g4 < 4; ++g4) {
        xi[g4] = *(const f16x8*)&rT[8*g4];
        xj[g4] = *(const f16x8*)&rS[8*g4];
    }
    #pragma unroll
    for (int g4 = 0; g4 < 4; ++g4) {
        bf16x8 v;
        #pragma unroll
        for (int u = 0; u < 8; ++u) {
            float m = (float)xi[g4][u] + (float)xj[g4][u] + b1[8*g4 + u];
            v[u] = (__bf16)siluf_(m);
        }
        ((bf16x8*)&sm[wid].ab[t][0])[g4] = v;
    }

    // B fragments of W2^T (bf16, [n][k]) + bias/gate vectors
    bf16x8 bfr[4];
    float b2v[4], gwv[4];
    #pragma unroll
    for (int ni = 0; ni < 4; ++ni) {
        bfr[ni] = *(const bf16x8*)&w2t[(16*ni + l15)*32 + quad*8];
        b2v[ni] = b2[16*ni + l15];
        gwv[ni] = gw[16*ni + l15];
    }
    float gb0 = gb[0];

    __syncthreads();  // ab + segTgt visible

    // ---- layer 2: 64x64 = 4x4 tiles, K=32 one MFMA each ----
    f32x4 acc[4][4];
    #pragma unroll
    for (int mi = 0; mi < 4; ++mi) {
        bf16x8 af = *(const bf16x8*)&sm[wid].ab[16*mi + l15][quad*8];
        #pragma unroll
        for (int ni = 0; ni < 4; ++ni) {
            f32x4 z = {0.f, 0.f, 0.f, 0.f};
            acc[mi][ni] = __builtin_amdgcn_mfma_f32_16x16x32_bf16(af, bfr[ni], z, 0, 0, 0);
        }
    }
    __syncthreads();  // ab frag reads done; union region free for bs

    // ---- epilogue: silu + gate, stash P = g*m2 in B-frag layout (f16) ----
    #pragma unroll
    for (int mi = 0; mi < 4; ++mi) {
        float sv[4][4]; // [ni][rg]
        #pragma unroll
        for (int ni = 0; ni < 4; ++ni)
            #pragma unroll
            for (int rg = 0; rg < 4; ++rg)
                sv[ni][rg] = siluf_(acc[mi][ni][rg] + b2v[ni]);
        float gg[4];
        #pragma unroll
        for (int rg = 0; rg < 4; ++rg) {
            float p = sv[0][rg]*gwv[0] + sv[1][rg]*gwv[1]
                    + sv[2][rg]*gwv[2] + sv[3][rg]*gwv[3];
            p += __shfl_xor(p, 1); p += __shfl_xor(p, 2);
            p += __shfl_xor(p, 4); p += __shfl_xor(p, 8);
            gg[rg] = sigmoidf_(p + gb0);
        }
        int c  = mi >> 1;
        int qb = 2*(mi & 1) + (quad >> 1);
        int j0 = 4*(quad & 1);
        #pragma unroll
        for (int ni = 0; ni < 4; ++ni) {
            f16x4 pk;
            #pragma unroll
            for (int rg = 0; rg < 4; ++rg) pk[rg] = (_Float16)(sv[ni][rg]*gg[rg]);
            *(f16x4*)&sm[wid].bs[c*4 + ni][16*qb + l15][j0] = pk;
        }
    }
    __syncthreads();  // bs visible

    // ---- indicator-MFMA segmented aggregation ----
    f16x8 bfrag[2][4];
    #pragma unroll
    for (int c = 0; c < 2; ++c)
        #pragma unroll
        for (int ni = 0; ni < 4; ++ni)
            bfrag[c][ni] = *(const f16x8*)&sm[wid].bs[c*4 + ni][t][0];

    float* ap = agg + (size_t)bt*NN*HH;
    for (int g0 = 0; g0 < nseg; g0 += 16) {
        f16x8 ind[2];
        #pragma unroll
        for (int c = 0; c < 2; ++c) {
            #pragma unroll
            for (int j = 0; j < 8; ++j) {
                int sj = __shfl(seg, 32*c + 8*quad + j);
                ind[c][j] = (sj == g0 + l15) ? (_Float16)1.0f : (_Float16)0.0f;
            }
        }
        f32x4 av[4];
        #pragma unroll
        for (int ni = 0; ni < 4; ++ni) {
            f32x4 z = {0.f, 0.f, 0.f, 0.f};
            av[ni] = __builtin_amdgcn_mfma_f32_16x16x32_f16(ind[0], bfrag[0][ni], z, 0, 0, 0);
            av[ni] = __builtin_amdgcn_mfma_f32_16x16x32_f16(ind[1], bfrag[1][ni], av[ni], 0, 0, 0);
        }
        #pragma unroll
        for (int rg = 0; rg < 4; ++rg) {
            int s = g0 + 4*quad + rg;   // C layout: row = quad*4 + reg
            if (s < nseg) {
                int tn = segTgt4[wid][s];
                #pragma unroll
                for (int ni = 0; ni < 4; ++ni)
                    atomicAdd(&ap[(size_t)tn*HH + 16*ni + l15], av[ni][rg]);
            }
        }
    }
}

// ---------------- spatial update (4 rows/wave) ----------------
__global__ void k_upd(const float* __restrict__ h, const float* __restrict__ agg,
                      const float* __restrict__ w1, const float* __restrict__ b1,
                      const float* __restrict__ w2, const float* __restrict__ b2,
                      float* __restrict__ out, int do_relu)
{
    int gid = blockIdx.x*blockDim.x + threadIdx.x;
    int wv_ = gid >> 6; int j = gid & 63;
    int r0 = wv_*4;
    if (r0 >= RR) return;
    r0 = __builtin_amdgcn_readfirstlane(r0);
    const float* ar = agg + (size_t)r0*HH;
    const float* hr = h   + (size_t)r0*HH;
    float bj = b1[j];
    float a0=bj,a1=bj,a2=bj,a3=bj;
    #pragma unroll 8
    for (int c = 0; c < 64; ++c) {
        float wv = w1[c*64 + j];
        a0 += ar[c]*wv; a1 += ar[HH+c]*wv; a2 += ar[2*HH+c]*wv; a3 += ar[3*HH+c]*wv;
    }
    #pragma unroll 8
    for (int c = 0; c < 64; ++c) {
        float wv = w1[(64+c)*64 + j];
        a0 += hr[c]*wv; a1 += hr[HH+c]*wv; a2 += hr[2*HH+c]*wv; a3 += hr[3*HH+c]*wv;
    }
    float u0=siluf_(a0), u1=siluf_(a1), u2=siluf_(a2), u3=siluf_(a3);
    float b2j = b2[j];
    float c0=b2j,c1=b2j,c2=b2j,c3=b2j;
    #pragma unroll 8
    for (int k2 = 0; k2 < 64; ++k2) {
        float wv = w2[k2*64 + j];
        c0 += __shfl(u0,k2)*wv; c1 += __shfl(u1,k2)*wv;
        c2 += __shfl(u2,k2)*wv; c3 += __shfl(u3,k2)*wv;
    }
    float o0 = c0 + hr[j],        o1 = c1 + hr[HH+j];
    float o2 = c2 + hr[2*HH+j],   o3 = c3 + hr[3*HH+j];
    if (do_relu) { o0=fmaxf(o0,0.f); o1=fmaxf(o1,0.f); o2=fmaxf(o2,0.f); o3=fmaxf(o3,0.f); }
    out[(size_t)r0*HH + j]        = o0;
    out[(size_t)r0*HH + HH + j]   = o1;
    out[(size_t)r0*HH + 2*HH + j] = o2;
    out[(size_t)r0*HH + 3*HH + j] = o3;
}

// ---------------- fused temporal: QKV + attention + Wo + sp2-pre ----------
// wave per (b,n); all T=12 steps resident in LDS/registers.
__global__ __launch_bounds__(64) void k_temporal(
    const float* __restrict__ h,
    const float* __restrict__ wq, const float* __restrict__ wk,
    const float* __restrict__ wv, const float* __restrict__ wo,
    const float* __restrict__ bq, const float* __restrict__ bk,
    const float* __restrict__ bv, const float* __restrict__ bo,
    const float* __restrict__ w1msg,
    float* __restrict__ hout, _Float16* __restrict__ preB)
{
    __shared__ float Qs[TT][68], Ks[TT][68], Vs[TT][68], Os[TT][68];
    int p = blockIdx.x;            // (b,n), 8000 blocks
    int b = p / NN, n = p % NN;
    int j = threadIdx.x;
    const size_t stride = (size_t)NN*HH;
    const size_t base0  = ((size_t)(b*TT)*NN + n)*HH;

    // ---- QKV: uniform s_loads of h rows, vector weight loads ----
    float qa[TT], ka[TT], va[TT];
    {
        float bqj = bq[j], bkj = bk[j], bvj = bv[j];
        #pragma unroll
        for (int t = 0; t < TT; ++t) { qa[t]=bqj; ka[t]=bkj; va[t]=bvj; }
    }
    #pragma unroll 4
    for (int c = 0; c < 64; ++c) {
        float wqc = wq[c*64 + j], wkc = wk[c*64 + j], wvc = wv[c*64 + j];
        #pragma unroll
        for (int t = 0; t < TT; ++t) {
            float hc = h[base0 + (size_t)t*stride + c];
            qa[t] += hc*wqc; ka[t] += hc*wkc; va[t] += hc*wvc;
        }
    }
    #pragma unroll
    for (int t = 0; t < TT; ++t) { Qs[t][j]=qa[t]; Ks[t][j]=ka[t]; Vs[t][j]=va[t]; }
    __syncthreads();

    // ---- attention: lane = (head,s), 96 pairs in 2 half-passes ----
    #pragma unroll
    for (int half = 0; half < 2; ++half) {
        if (j < 48) {
            int head = half*4 + j/12;
            int s    = j % 12;
            f32x4 qv0 = *(const f32x4*)&Qs[s][head*8];
            f32x4 qv1 = *(const f32x4*)&Qs[s][head*8 + 4];
            float sc[TT]; float mx = -1e30f;
            #pragma unroll
            for (int t = 0; t < TT; ++t) {
                f32x4 k0 = *(const f32x4*)&Ks[t][head*8];
                f32x4 k1 = *(const f32x4*)&Ks[t][head*8 + 4];
                float a = qv0[0]*k0[0] + qv0[1]*k0[1] + qv0[2]*k0[2] + qv0[3]*k0[3]
                        + qv1[0]*k1[0] + qv1[1]*k1[1] + qv1[2]*k1[2] + qv1[3]*k1[3];
                a *= 0.35355339059327373f;
                sc[t] = a; mx = fmaxf(mx, a);
            }
            float sum = 0.f;
            #pragma unroll
            for (int t = 0; t < TT; ++t) { sc[t] = __expf(sc[t]-mx); sum += sc[t]; }
            float inv = 1.0f/sum;
            f32x4 o0 = {0.f,0.f,0.f,0.f}, o1 = {0.f,0.f,0.f,0.f};
            #pragma unroll
            for (int t = 0; t < TT; ++t) {
                float a = sc[t]*inv;
                f32x4 v0 = *(const f32x4*)&Vs[t][head*8];
                f32x4 v1 = *(const f32x4*)&Vs[t][head*8 + 4];
                o0[0]+=a*v0[0]; o0[1]+=a*v0[1]; o0[2]+=a*v0[2]; o0[3]+=a*v0[3];
                o1[0]+=a*v1[0]; o1[1]+=a*v1[1]; o1[2]+=a*v1[2]; o1[3]+=a*v1[3];
            }
            *(f32x4*)&Os[s][head*8]     = o0;
            *(f32x4*)&Os[s][head*8 + 4] = o1;
        }
    }
    __syncthreads();

    // ---- Wo projection via readlane broadcasts ----
    float oreg[TT];
    #pragma unroll
    for (int t = 0; t < TT; ++t) oreg[t] = Os[t][j];
    float hn[TT];
    {
        float boj = bo[j];
        #pragma unroll
        for (int t = 0; t < TT; ++t) hn[t] = boj;
    }
    #pragma unroll 4
    for (int c = 0; c < 64; ++c) {
        float woc = wo[c*64 + j];
        #pragma unroll
        for (int t = 0; t < TT; ++t) hn[t] += __shfl(oreg[t], c)*woc;
    }
    #pragma unroll
    for (int t = 0; t < TT; ++t) hout[base0 + (size_t)t*stride + j] = hn[t];

    // ---- fused sp2 msg-layer-1 precompute ----
    int basew = (j < 32) ? j : (2048 + j - 32);
    float pr[TT];
    #pragma unroll
    for (int t = 0; t < TT; ++t) pr[t] = 0.f;
    #pragma unroll 4
    for (int c = 0; c < 64; ++c) {
        float w1c = w1msg[c*32 + basew];
        #pragma unroll
        for (int t = 0; t < TT; ++t) pr[t] += __shfl(hn[t], c)*w1c;
    }
    #pragma unroll
    for (int t = 0; t < TT; ++t)
        preB[base0 + (size_t)t*stride + j] = (_Float16)pr[t];
}

// ---------------- conv head stage 1: z[b,hor,n,0:72] ----------------------
__global__ __launch_bounds__(256) void k_zbuild(
    const float* __restrict__ h, const float* __restrict__ x,
    const float* __restrict__ cw, const float* __restrict__ cb,
    float* __restrict__ z)
{
    int gid = blockIdx.x*blockDim.x + threadIdx.x;
    int p = gid >> 6;          // (b,n) pair, 8000 total
    int j = gid & 63;
    if (p >= BB*NN) return;
    p = __builtin_amdgcn_readfirstlane(p);
    int b = p / NN, n = p % NN;

    float hv[TT];
    #pragma unroll
    for (int t = 0; t < TT; ++t)
        hv[t] = h[((size_t)(b*TT + t)*NN + n)*HH + j];
    float xv[TT];
    if (j < CC) {
        #pragma unroll
        for (int t = 0; t < TT; ++t)
            xv[t] = x[((size_t)(b*TT + t)*NN + n)*CC + j];
    }

    #pragma unroll
    for (int hor = 0; hor < HORZ; ++hor) {
        float cbv = cb[hor];
        float zh = cbv, zx = cbv;
        #pragma unroll
        for (int t = 0; t < TT; ++t) {
            float w = cw[hor*TT + t];
            zh += w*hv[t];
            if (j < CC) zx += w*xv[t];
        }
        size_t row = (size_t)(b*HORZ + hor)*NN + n;
        z[row*72 + j] = zh;
        if (j < CC) z[row*72 + 64 + j] = zx;
    }
}

// ---------------- conv head stage 2: out = relu(z@w1+b1)@w2+b2 ------------
__global__ __launch_bounds__(256) void k_headmlp(
    const float* __restrict__ z,
    const float* __restrict__ w1, const float* __restrict__ b1,
    const float* __restrict__ w2, const float* __restrict__ b2,
    float* __restrict__ out)
{
    __shared__ float U[4][4][65];
    int gid = blockIdx.x*blockDim.x + threadIdx.x;
    int wv_ = gid >> 6; int j = gid & 63;
    int wl = threadIdx.x >> 6;
    int r0 = wv_*4;
    r0 = __builtin_amdgcn_readfirstlane(r0);
    const float* zr = z + (size_t)r0*72;
    float bj = b1[j];
    float a0=bj,a1=bj,a2=bj,a3=bj;
    #pragma unroll 8
    for (int c = 0; c < 72; ++c) {
        float wc = w1[c*64 + j];
        a0 += zr[c]*wc; a1 += zr[72+c]*wc; a2 += zr[144+c]*wc; a3 += zr[216+c]*wc;
    }
    U[wl][0][j] = fmaxf(a0, 0.f);
    U[wl][1][j] = fmaxf(a1, 0.f);
    U[wl][2][j] = fmaxf(a2, 0.f);
    U[wl][3][j] = fmaxf(a3, 0.f);
    __syncthreads();

    if (j < 32) {
        int r = j >> 3, c = j & 7;
        float o = b2[c];
        #pragma unroll 8
        for (int k = 0; k < 64; ++k)
            o += U[wl][r][k] * w2[k*8 + c];
        out[(size_t)(r0 + r)*CC + c] = o;
    }
}

extern "C" void kernel_launch(void* const* d_in, const int* in_sizes, int n_in,
                              void* d_out, int out_size, void* d_ws, size_t ws_size,
                              hipStream_t stream) {
    const float* x    = (const float*)d_in[0];
    const int*   eidx = (const int*)d_in[1];
    const float* up_w = (const float*)d_in[2];
    const float* up_b = (const float*)d_in[3];
    const float* sp_w[2][10];
    for (int p = 0; p < 2; ++p)
        for (int i = 0; i < 10; ++i)
            sp_w[p][i] = (const float*)d_in[4 + p*10 + i];
    const float* wq = (const float*)d_in[24];
    const float* wk = (const float*)d_in[25];
    const float* wv = (const float*)d_in[26];
    const float* wo = (const float*)d_in[27];
    const float* bq = (const float*)d_in[28];
    const float* bk = (const float*)d_in[29];
    const float* bv = (const float*)d_in[30];
    const float* bo = (const float*)d_in[31];
    const float* conv_w = (const float*)d_in[32];
    const float* conv_b = (const float*)d_in[33];
    const float* mlp_w1 = (const float*)d_in[34];
    const float* mlp_b1 = (const float*)d_in[35];
    const float* mlp_w2 = (const float*)d_in[36];
    const float* mlp_b2 = (const float*)d_in[37];
    float* out = (float*)d_out;

    const size_t BUF = (size_t)RR*HH;      // 6,144,000 elements
    float* A    = (float*)d_ws;            // h
    float* Bb   = A   + BUF;               // h2
    float* AGG  = Bb  + BUF;               // agg
    _Float16* PRE = (_Float16*)(AGG + BUF);// first-layer precompute (f16, 12.3MB)
    int*   cnt      = (int*)(PRE + BUF);   // 2048
    int*   ofs_work = cnt + 2048;          // 2048
    int*   ssrc     = ofs_work + 2048;     // EE
    int*   stgt     = ssrc + EE;           // EE
    __bf16* w2t0    = (__bf16*)(stgt + EE);// 2048 bf16
    __bf16* w2t1    = w2t0 + 2048;
    float* Z = AGG;   // z[96000*72] = 27.6 MB overlays AGG+PRE (both dead by then)

    const int G4 = RR/16;                  // 6000 blocks of 256 (4 rows/wave)

    // ---- CSR build + weight prep ----
    hipMemsetAsync(cnt, 0, 2048*sizeof(int), stream);
    k_hist<<<(EE+255)/256, 256, 0, stream>>>(eidx, cnt);
    k_w2prep<<<8, 256, 0, stream>>>(sp_w[0][2], w2t0);
    k_w2prep<<<8, 256, 0, stream>>>(sp_w[1][2], w2t1);
    k_scan<<<1, 256, 0, stream>>>(cnt, ofs_work);
    k_scatter<<<(EE+255)/256, 256, 0, stream>>>(eidx, ofs_work, ssrc, stgt);

    // 1. up-projection + sp1 pre (fused)
    k_up<<<G4, 256, 0, stream>>>(x, up_w, up_b, sp_w[0][0], A, PRE);

    // 2. spatial 1
    hipMemsetAsync(AGG, 0, BUF*sizeof(float), stream);
    k_msg<<<12*(EE/64), 256, 0, stream>>>(PRE, ssrc, stgt,
        sp_w[0][1], w2t0, sp_w[0][3], sp_w[0][4], sp_w[0][5], AGG);
    k_upd<<<G4, 256, 0, stream>>>(A, AGG,
        sp_w[0][6], sp_w[0][7], sp_w[0][8], sp_w[0][9], Bb, 1);

    // 3. fused temporal (Bb -> A) + sp2 pre (fused)
    k_temporal<<<BB*NN, 64, 0, stream>>>(Bb, wq, wk, wv, wo, bq, bk, bv, bo,
        sp_w[1][0], A, PRE);

    // 4. spatial 2
    hipMemsetAsync(AGG, 0, BUF*sizeof(float), stream);
    k_msg<<<12*(EE/64), 256, 0, stream>>>(PRE, ssrc, stgt,
        sp_w[1][1], w2t1, sp_w[1][3], sp_w[1][4], sp_w[1][5], AGG);
    k_upd<<<G4, 256, 0, stream>>>(A, AGG,
        sp_w[1][6], sp_w[1][7], sp_w[1][8], sp_w[1][9], Bb, 1);

    // 5. conv + MLP head: zbuild (Z overlays AGG/PRE, both dead) -> out
    k_zbuild<<<(BB*NN*64 + 255)/256, 256, 0, stream>>>(Bb, x, conv_w, conv_b, Z);
    k_headmlp<<<(BB*HORZ*NN)/16, 256, 0, stream>>>(Z,
        mlp_w1, mlp_b1, mlp_w2, mlp_b2, out);
}

// Round 7
// 738.484 us; speedup vs baseline: 1.0258x; 1.0258x over previous
//
#include <hip/hip_runtime.h>
#include <math.h>

#define BB 4
#define TT 12
#define NN 2000
#define CC 8
#define HH 64
#define EE 32000
#define NHEADS 8
#define HD 8
#define HORZ 12
#define BT (BB*TT)        // 48
#define RR (BT*NN)        // 96000 rows of H=64

using bf16x8 = __attribute__((ext_vector_type(8))) __bf16;
using f16x8  = __attribute__((ext_vector_type(8))) _Float16;
using f16x4  = __attribute__((ext_vector_type(4))) _Float16;
using f32x4  = __attribute__((ext_vector_type(4))) float;

__device__ __forceinline__ float sigmoidf_(float x){ return 1.0f/(1.0f+__expf(-x)); }
__device__ __forceinline__ float siluf_(float x){ return x/(1.0f+__expf(-x)); }

// ================= CSR build (edges sorted by tgt) =================
__global__ void k_hist(const int* __restrict__ eidx, int* __restrict__ cnt) {
    int e = blockIdx.x*blockDim.x + threadIdx.x;
    if (e < EE) atomicAdd(&cnt[eidx[EE + e]], 1);
}

__global__ __launch_bounds__(256) void k_scan(const int* __restrict__ cnt,
                                              int* __restrict__ ofs_work) {
    __shared__ int part[256];
    int tid = threadIdx.x;
    int local[8]; int s = 0;
    #pragma unroll
    for (int k = 0; k < 8; ++k) {
        int idx = tid*8 + k;
        int v = (idx < NN) ? cnt[idx] : 0;
        local[k] = s; s += v;
    }
    part[tid] = s; __syncthreads();
    for (int off = 1; off < 256; off <<= 1) {
        int v = part[tid];
        int u = (tid >= off) ? part[tid-off] : 0;
        __syncthreads();
        part[tid] = v + u;
        __syncthreads();
    }
    int excl = part[tid] - s;
    #pragma unroll
    for (int k = 0; k < 8; ++k) {
        int idx = tid*8 + k;
        if (idx < NN) ofs_work[idx] = excl + local[k];
    }
}

__global__ void k_scatter(const int* __restrict__ eidx, int* __restrict__ ofs_work,
                          int* __restrict__ ssrc, int* __restrict__ stgt) {
    int e = blockIdx.x*blockDim.x + threadIdx.x;
    if (e >= EE) return;
    int t = eidx[EE + e];
    int pos = atomicAdd(&ofs_work[t], 1);
    ssrc[pos] = eidx[e];
    stgt[pos] = t;
}

// ========== W2 -> bf16, transposed to B-fragment-friendly [n][k] ==========
__global__ void k_w2prep(const float* __restrict__ w2, __bf16* __restrict__ w2t) {
    int i = blockIdx.x*blockDim.x + threadIdx.x;  // 2048 = 64 n * 32 k
    if (i >= 2048) return;
    int n = i >> 5, k = i & 31;
    w2t[i] = (__bf16)w2[k*64 + n];
}

// ---------------- up-projection + fused sp1 msg-layer-1 precompute -------
__global__ void k_up(const float* __restrict__ x, const float* __restrict__ w,
                     const float* __restrict__ b, const float* __restrict__ w1msg,
                     float* __restrict__ h, _Float16* __restrict__ preB) {
    int gid = blockIdx.x*blockDim.x + threadIdx.x;
    int wv_ = gid >> 6; int j = gid & 63;
    int r0 = wv_*4;
    if (r0 >= RR) return;
    r0 = __builtin_amdgcn_readfirstlane(r0);
    const float* xr = x + (size_t)r0*CC;
    float bj = b[j];
    float a0=bj,a1=bj,a2=bj,a3=bj;
    #pragma unroll
    for (int c = 0; c < CC; ++c) {
        float wc = w[c*HH + j];
        a0 += xr[c]*wc; a1 += xr[CC+c]*wc; a2 += xr[2*CC+c]*wc; a3 += xr[3*CC+c]*wc;
    }
    a0 = fmaxf(a0, 0.f); a1 = fmaxf(a1, 0.f); a2 = fmaxf(a2, 0.f); a3 = fmaxf(a3, 0.f);
    h[(size_t)r0*HH + j]        = a0;
    h[(size_t)r0*HH + HH + j]   = a1;
    h[(size_t)r0*HH + 2*HH + j] = a2;
    h[(size_t)r0*HH + 3*HH + j] = a3;

    int base = (j < 32) ? j : (2048 + j - 32);
    float p0=0.f,p1=0.f,p2=0.f,p3=0.f;
    #pragma unroll
    for (int c = 0; c < 64; ++c) {
        float w1c = w1msg[c*32 + base];
        p0 += __shfl(a0, c)*w1c; p1 += __shfl(a1, c)*w1c;
        p2 += __shfl(a2, c)*w1c; p3 += __shfl(a3, c)*w1c;
    }
    preB[(size_t)r0*HH + j]        = (_Float16)p0;
    preB[(size_t)r0*HH + HH + j]   = (_Float16)p1;
    preB[(size_t)r0*HH + 2*HH + j] = (_Float16)p2;
    preB[(size_t)r0*HH + 3*HH + j] = (_Float16)p3;
}

// ========== message MLP + gate + indicator-MFMA segmented aggregation =====
// (R5 64-thread version — known-good 112 µs)
__global__ __launch_bounds__(64) void k_msg(
    const _Float16* __restrict__ preB, const int* __restrict__ ssrc,
    const int* __restrict__ stgt,
    const float* __restrict__ b1,
    const __bf16* __restrict__ w2t, const float* __restrict__ b2,
    const float* __restrict__ gw, const float* __restrict__ gb,
    float* __restrict__ agg)
{
    const int EB = EE/64; // 500
    int eb = blockIdx.x % EB;
    int bt = blockIdx.x / EB;
    int t  = threadIdx.x;
    int l15 = t & 15, quad = t >> 4;

    union __align__(16) SM {
        __bf16   ab[64][40];
        _Float16 bs[8][64][8];
    };
    __shared__ SM sm;
    __shared__ int segTgt[64];

    int e0 = eb*64;
    int my_src = ssrc[e0 + t];
    int my_tgt = stgt[e0 + t];

    int prevt = __shfl(my_tgt, (t + 63) & 63);
    bool bnd = (t == 0) || (prevt != my_tgt);
    unsigned long long bm = __ballot(bnd);
    int seg = __builtin_amdgcn_mbcnt_hi((unsigned)(bm >> 32),
              __builtin_amdgcn_mbcnt_lo((unsigned)bm, 0u));
    int nseg = __popcll(bm);
    if (bnd) segTgt[seg] = my_tgt;

    const _Float16* basep = preB + (size_t)bt*NN*HH;
    const _Float16* rT = basep + (size_t)my_tgt*HH;
    const _Float16* rS = basep + (size_t)my_src*HH + 32;
    f16x8 xi[4], xj[4];
    #pragma unroll
    for (int g4 = 0; g4 < 4; ++g4) {
        xi[g4] = *(const f16x8*)&rT[8*g4];
        xj[g4] = *(const f16x8*)&rS[8*g4];
    }
    #pragma unroll
    for (int g4 = 0; g4 < 4; ++g4) {
        bf16x8 v;
        #pragma unroll
        for (int u = 0; u < 8; ++u) {
            float m = (float)xi[g4][u] + (float)xj[g4][u] + b1[8*g4 + u];
            v[u] = (__bf16)siluf_(m);
        }
        ((bf16x8*)&sm.ab[t][0])[g4] = v;
    }

    bf16x8 bfr[4];
    float b2v[4], gwv[4];
    #pragma unroll
    for (int ni = 0; ni < 4; ++ni) {
        bfr[ni] = *(const bf16x8*)&w2t[(16*ni + l15)*32 + quad*8];
        b2v[ni] = b2[16*ni + l15];
        gwv[ni] = gw[16*ni + l15];
    }
    float gb0 = gb[0];

    __syncthreads();

    f32x4 acc[4][4];
    #pragma unroll
    for (int mi = 0; mi < 4; ++mi) {
        bf16x8 af = *(const bf16x8*)&sm.ab[16*mi + l15][quad*8];
        #pragma unroll
        for (int ni = 0; ni < 4; ++ni) {
            f32x4 z = {0.f, 0.f, 0.f, 0.f};
            acc[mi][ni] = __builtin_amdgcn_mfma_f32_16x16x32_bf16(af, bfr[ni], z, 0, 0, 0);
        }
    }
    __syncthreads();

    #pragma unroll
    for (int mi = 0; mi < 4; ++mi) {
        float sv[4][4];
        #pragma unroll
        for (int ni = 0; ni < 4; ++ni)
            #pragma unroll
            for (int rg = 0; rg < 4; ++rg)
                sv[ni][rg] = siluf_(acc[mi][ni][rg] + b2v[ni]);
        float gg[4];
        #pragma unroll
        for (int rg = 0; rg < 4; ++rg) {
            float p = sv[0][rg]*gwv[0] + sv[1][rg]*gwv[1]
                    + sv[2][rg]*gwv[2] + sv[3][rg]*gwv[3];
            p += __shfl_xor(p, 1); p += __shfl_xor(p, 2);
            p += __shfl_xor(p, 4); p += __shfl_xor(p, 8);
            gg[rg] = sigmoidf_(p + gb0);
        }
        int c  = mi >> 1;
        int qb = 2*(mi & 1) + (quad >> 1);
        int j0 = 4*(quad & 1);
        #pragma unroll
        for (int ni = 0; ni < 4; ++ni) {
            f16x4 pk;
            #pragma unroll
            for (int rg = 0; rg < 4; ++rg) pk[rg] = (_Float16)(sv[ni][rg]*gg[rg]);
            *(f16x4*)&sm.bs[c*4 + ni][16*qb + l15][j0] = pk;
        }
    }
    __syncthreads();

    f16x8 bfrag[2][4];
    #pragma unroll
    for (int c = 0; c < 2; ++c)
        #pragma unroll
        for (int ni = 0; ni < 4; ++ni)
            bfrag[c][ni] = *(const f16x8*)&sm.bs[c*4 + ni][t][0];

    float* ap = agg + (size_t)bt*NN*HH;
    for (int g0 = 0; g0 < nseg; g0 += 16) {
        f16x8 ind[2];
        #pragma unroll
        for (int c = 0; c < 2; ++c) {
            #pragma unroll
            for (int j = 0; j < 8; ++j) {
                int sj = __shfl(seg, 32*c + 8*quad + j);
                ind[c][j] = (sj == g0 + l15) ? (_Float16)1.0f : (_Float16)0.0f;
            }
        }
        f32x4 av[4];
        #pragma unroll
        for (int ni = 0; ni < 4; ++ni) {
            f32x4 z = {0.f, 0.f, 0.f, 0.f};
            av[ni] = __builtin_amdgcn_mfma_f32_16x16x32_f16(ind[0], bfrag[0][ni], z, 0, 0, 0);
            av[ni] = __builtin_amdgcn_mfma_f32_16x16x32_f16(ind[1], bfrag[1][ni], av[ni], 0, 0, 0);
        }
        #pragma unroll
        for (int rg = 0; rg < 4; ++rg) {
            int s = g0 + 4*quad + rg;
            if (s < nseg) {
                int tn = segTgt[s];
                #pragma unroll
                for (int ni = 0; ni < 4; ++ni)
                    atomicAdd(&ap[(size_t)tn*HH + 16*ni + l15], av[ni][rg]);
            }
        }
    }
}

// ---------------- spatial update (4 rows/wave) ----------------
__global__ void k_upd(const float* __restrict__ h, const float* __restrict__ agg,
                      const float* __restrict__ w1, const float* __restrict__ b1,
                      const float* __restrict__ w2, const float* __restrict__ b2,
                      float* __restrict__ out, int do_relu)
{
    int gid = blockIdx.x*blockDim.x + threadIdx.x;
    int wv_ = gid >> 6; int j = gid & 63;
    int r0 = wv_*4;
    if (r0 >= RR) return;
    r0 = __builtin_amdgcn_readfirstlane(r0);
    const float* ar = agg + (size_t)r0*HH;
    const float* hr = h   + (size_t)r0*HH;
    float bj = b1[j];
    float a0=bj,a1=bj,a2=bj,a3=bj;
    #pragma unroll 8
    for (int c = 0; c < 64; ++c) {
        float wv = w1[c*64 + j];
        a0 += ar[c]*wv; a1 += ar[HH+c]*wv; a2 += ar[2*HH+c]*wv; a3 += ar[3*HH+c]*wv;
    }
    #pragma unroll 8
    for (int c = 0; c < 64; ++c) {
        float wv = w1[(64+c)*64 + j];
        a0 += hr[c]*wv; a1 += hr[HH+c]*wv; a2 += hr[2*HH+c]*wv; a3 += hr[3*HH+c]*wv;
    }
    float u0=siluf_(a0), u1=siluf_(a1), u2=siluf_(a2), u3=siluf_(a3);
    float b2j = b2[j];
    float c0=b2j,c1=b2j,c2=b2j,c3=b2j;
    #pragma unroll 8
    for (int k2 = 0; k2 < 64; ++k2) {
        float wv = w2[k2*64 + j];
        c0 += __shfl(u0,k2)*wv; c1 += __shfl(u1,k2)*wv;
        c2 += __shfl(u2,k2)*wv; c3 += __shfl(u3,k2)*wv;
    }
    float o0 = c0 + hr[j],        o1 = c1 + hr[HH+j];
    float o2 = c2 + hr[2*HH+j],   o3 = c3 + hr[3*HH+j];
    if (do_relu) { o0=fmaxf(o0,0.f); o1=fmaxf(o1,0.f); o2=fmaxf(o2,0.f); o3=fmaxf(o3,0.f); }
    out[(size_t)r0*HH + j]        = o0;
    out[(size_t)r0*HH + HH + j]   = o1;
    out[(size_t)r0*HH + 2*HH + j] = o2;
    out[(size_t)r0*HH + 3*HH + j] = o3;
}

// ---------------- fused QKV projection (4 rows/wave) ----------------
__global__ void k_qkv(const float* __restrict__ h,
                      const float* __restrict__ wq, const float* __restrict__ wk,
                      const float* __restrict__ wv,
                      const float* __restrict__ bq, const float* __restrict__ bk,
                      const float* __restrict__ bv,
                      float* __restrict__ q, float* __restrict__ k, float* __restrict__ v)
{
    int gid = blockIdx.x*blockDim.x + threadIdx.x;
    int wv_ = gid >> 6; int j = gid & 63;
    int r0 = wv_*4;
    if (r0 >= RR) return;
    r0 = __builtin_amdgcn_readfirstlane(r0);
    const float* hr = h + (size_t)r0*HH;
    float q0=bq[j],q1=q0,q2=q0,q3=q0;
    float k0=bk[j],k1=k0,k2v=k0,k3=k0;
    float v0=bv[j],v1=v0,v2=v0,v3=v0;
    #pragma unroll 4
    for (int c = 0; c < 64; ++c) {
        float wqc = wq[c*64 + j], wkc = wk[c*64 + j], wvc = wv[c*64 + j];
        float h0 = hr[c], h1 = hr[HH+c], h2 = hr[2*HH+c], h3 = hr[3*HH+c];
        q0 += h0*wqc; q1 += h1*wqc; q2 += h2*wqc; q3 += h3*wqc;
        k0 += h0*wkc; k1 += h1*wkc; k2v += h2*wkc; k3 += h3*wkc;
        v0 += h0*wvc; v1 += h1*wvc; v2 += h2*wvc; v3 += h3*wvc;
    }
    size_t o = (size_t)r0*HH + j;
    q[o]=q0; q[o+HH]=q1; q[o+2*HH]=q2; q[o+3*HH]=q3;
    k[o]=k0; k[o+HH]=k1; k[o+2*HH]=k2v; k[o+3*HH]=k3;
    v[o]=v0; v[o+HH]=v1; v[o+2*HH]=v2; v[o+3*HH]=v3;
}

// ---------------- temporal attention (T=12, per (b,n,head,s) thread) ------
__global__ void k_attn(const float* __restrict__ q, const float* __restrict__ k,
                       const float* __restrict__ v, float* __restrict__ o)
{
    int gid = blockIdx.x*blockDim.x + threadIdx.x;
    if (gid >= BB*NN*NHEADS*TT) return;
    int s    = gid % TT;
    int head = (gid/TT) % NHEADS;
    int n    = (gid/(TT*NHEADS)) % NN;
    int b    = gid/(TT*NHEADS*NN);

    float qv[HD];
    size_t qoff = ((size_t)(b*TT + s)*NN + n)*HH + head*HD;
    #pragma unroll
    for (int d = 0; d < HD; ++d) qv[d] = q[qoff + d];

    float sc[TT]; float mx = -1e30f;
    #pragma unroll
    for (int t = 0; t < TT; ++t) {
        size_t koff = ((size_t)(b*TT + t)*NN + n)*HH + head*HD;
        float a = 0.f;
        #pragma unroll
        for (int d = 0; d < HD; ++d) a += qv[d]*k[koff + d];
        a *= 0.35355339059327373f;
        sc[t] = a; mx = fmaxf(mx, a);
    }
    float sum = 0.f;
    #pragma unroll
    for (int t = 0; t < TT; ++t) { sc[t] = __expf(sc[t]-mx); sum += sc[t]; }
    float inv = 1.0f/sum;
    float ov[HD];
    #pragma unroll
    for (int d = 0; d < HD; ++d) ov[d] = 0.f;
    #pragma unroll
    for (int t = 0; t < TT; ++t) {
        size_t voff = ((size_t)(b*TT + t)*NN + n)*HH + head*HD;
        float a = sc[t]*inv;
        #pragma unroll
        for (int d = 0; d < HD; ++d) ov[d] += a*v[voff + d];
    }
    #pragma unroll
    for (int d = 0; d < HD; ++d) o[qoff + d] = ov[d];
}

// ---------------- Wo projection + fused sp2 msg-layer-1 pre ----------------
__global__ void k_wo_pre(const float* __restrict__ in, const float* __restrict__ w,
                         const float* __restrict__ b, const float* __restrict__ w1msg,
                         float* __restrict__ out, _Float16* __restrict__ preB)
{
    int gid = blockIdx.x*blockDim.x + threadIdx.x;
    int wv_ = gid >> 6; int j = gid & 63;
    int r0 = wv_*4;
    if (r0 >= RR) return;
    r0 = __builtin_amdgcn_readfirstlane(r0);
    const float* ir = in + (size_t)r0*HH;
    float bj = b[j];
    float a0=bj,a1=bj,a2=bj,a3=bj;
    #pragma unroll 8
    for (int c = 0; c < 64; ++c) {
        float wc = w[c*64 + j];
        a0 += ir[c]*wc; a1 += ir[HH+c]*wc; a2 += ir[2*HH+c]*wc; a3 += ir[3*HH+c]*wc;
    }
    out[(size_t)r0*HH + j]        = a0;
    out[(size_t)r0*HH + HH + j]   = a1;
    out[(size_t)r0*HH + 2*HH + j] = a2;
    out[(size_t)r0*HH + 3*HH + j] = a3;

    int base = (j < 32) ? j : (2048 + j - 32);
    float p0=0.f,p1=0.f,p2=0.f,p3=0.f;
    #pragma unroll
    for (int c = 0; c < 64; ++c) {
        float w1c = w1msg[c*32 + base];
        p0 += __shfl(a0, c)*w1c; p1 += __shfl(a1, c)*w1c;
        p2 += __shfl(a2, c)*w1c; p3 += __shfl(a3, c)*w1c;
    }
    preB[(size_t)r0*HH + j]        = (_Float16)p0;
    preB[(size_t)r0*HH + HH + j]   = (_Float16)p1;
    preB[(size_t)r0*HH + 2*HH + j] = (_Float16)p2;
    preB[(size_t)r0*HH + 3*HH + j] = (_Float16)p3;
}

// ---------------- conv head stage 1: z[b,hor,n,0:72] ----------------------
__global__ __launch_bounds__(256) void k_zbuild(
    const float* __restrict__ h, const float* __restrict__ x,
    const float* __restrict__ cw, const float* __restrict__ cb,
    float* __restrict__ z)
{
    int gid = blockIdx.x*blockDim.x + threadIdx.x;
    int p = gid >> 6;
    int j = gid & 63;
    if (p >= BB*NN) return;
    p = __builtin_amdgcn_readfirstlane(p);
    int b = p / NN, n = p % NN;

    float hv[TT];
    #pragma unroll
    for (int t = 0; t < TT; ++t)
        hv[t] = h[((size_t)(b*TT + t)*NN + n)*HH + j];
    float xv[TT];
    if (j < CC) {
        #pragma unroll
        for (int t = 0; t < TT; ++t)
            xv[t] = x[((size_t)(b*TT + t)*NN + n)*CC + j];
    }

    #pragma unroll
    for (int hor = 0; hor < HORZ; ++hor) {
        float cbv = cb[hor];
        float zh = cbv, zx = cbv;
        #pragma unroll
        for (int t = 0; t < TT; ++t) {
            float w = cw[hor*TT + t];
            zh += w*hv[t];
            if (j < CC) zx += w*xv[t];
        }
        size_t row = (size_t)(b*HORZ + hor)*NN + n;
        z[row*72 + j] = zh;
        if (j < CC) z[row*72 + 64 + j] = zx;
    }
}

// ---------------- conv head stage 2: out = relu(z@w1+b1)@w2+b2 ------------
__global__ __launch_bounds__(256) void k_headmlp(
    const float* __restrict__ z,
    const float* __restrict__ w1, const float* __restrict__ b1,
    const float* __restrict__ w2, const float* __restrict__ b2,
    float* __restrict__ out)
{
    __shared__ float U[4][4][65];
    int gid = blockIdx.x*blockDim.x + threadIdx.x;
    int wv_ = gid >> 6; int j = gid & 63;
    int wl = threadIdx.x >> 6;
    int r0 = wv_*4;
    r0 = __builtin_amdgcn_readfirstlane(r0);
    const float* zr = z + (size_t)r0*72;
    float bj = b1[j];
    float a0=bj,a1=bj,a2=bj,a3=bj;
    #pragma unroll 8
    for (int c = 0; c < 72; ++c) {
        float wc = w1[c*64 + j];
        a0 += zr[c]*wc; a1 += zr[72+c]*wc; a2 += zr[144+c]*wc; a3 += zr[216+c]*wc;
    }
    U[wl][0][j] = fmaxf(a0, 0.f);
    U[wl][1][j] = fmaxf(a1, 0.f);
    U[wl][2][j] = fmaxf(a2, 0.f);
    U[wl][3][j] = fmaxf(a3, 0.f);
    __syncthreads();

    if (j < 32) {
        int r = j >> 3, c = j & 7;
        float o = b2[c];
        #pragma unroll 8
        for (int k = 0; k < 64; ++k)
            o += U[wl][r][k] * w2[k*8 + c];
        out[(size_t)(r0 + r)*CC + c] = o;
    }
}

extern "C" void kernel_launch(void* const* d_in, const int* in_sizes, int n_in,
                              void* d_out, int out_size, void* d_ws, size_t ws_size,
                              hipStream_t stream) {
    const float* x    = (const float*)d_in[0];
    const int*   eidx = (const int*)d_in[1];
    const float* up_w = (const float*)d_in[2];
    const float* up_b = (const float*)d_in[3];
    const float* sp_w[2][10];
    for (int p = 0; p < 2; ++p)
        for (int i = 0; i < 10; ++i)
            sp_w[p][i] = (const float*)d_in[4 + p*10 + i];
    const float* wq = (const float*)d_in[24];
    const float* wk = (const float*)d_in[25];
    const float* wv = (const float*)d_in[26];
    const float* wo = (const float*)d_in[27];
    const float* bq = (const float*)d_in[28];
    const float* bk = (const float*)d_in[29];
    const float* bv = (const float*)d_in[30];
    const float* bo = (const float*)d_in[31];
    const float* conv_w = (const float*)d_in[32];
    const float* conv_b = (const float*)d_in[33];
    const float* mlp_w1 = (const float*)d_in[34];
    const float* mlp_b1 = (const float*)d_in[35];
    const float* mlp_w2 = (const float*)d_in[36];
    const float* mlp_b2 = (const float*)d_in[37];
    float* out = (float*)d_out;

    const size_t BUF = (size_t)RR*HH;      // 6,144,000 elements
    float* A    = (float*)d_ws;            // h / Q
    float* Bb   = A   + BUF;               // h2
    float* AGG  = Bb  + BUF;               // agg / K
    float* Vb   = AGG + BUF;               // V
    float* Ob   = Vb  + BUF;               // attn out
    _Float16* PRE = (_Float16*)(Ob + BUF); // first-layer precompute (f16)
    int*   cnt      = (int*)(PRE + BUF);
    int*   ofs_work = cnt + 2048;
    int*   ssrc     = ofs_work + 2048;
    int*   stgt     = ssrc + EE;
    __bf16* w2t0    = (__bf16*)(stgt + EE);
    __bf16* w2t1    = w2t0 + 2048;
    float* Z = AGG;   // z (27.6 MB) overlays AGG+Vb (dead by then)

    const int G4 = RR/16;                  // 6000 blocks of 256 (4 rows/wave)

    // ---- CSR build + weight prep ----
    hipMemsetAsync(cnt, 0, 2048*sizeof(int), stream);
    k_hist<<<(EE+255)/256, 256, 0, stream>>>(eidx, cnt);
    k_w2prep<<<8, 256, 0, stream>>>(sp_w[0][2], w2t0);
    k_w2prep<<<8, 256, 0, stream>>>(sp_w[1][2], w2t1);
    k_scan<<<1, 256, 0, stream>>>(cnt, ofs_work);
    k_scatter<<<(EE+255)/256, 256, 0, stream>>>(eidx, ofs_work, ssrc, stgt);

    // 1. up-projection + sp1 pre (fused)
    k_up<<<G4, 256, 0, stream>>>(x, up_w, up_b, sp_w[0][0], A, PRE);

    // 2. spatial 1
    hipMemsetAsync(AGG, 0, BUF*sizeof(float), stream);
    k_msg<<<BT*(EE/64), 64, 0, stream>>>(PRE, ssrc, stgt,
        sp_w[0][1], w2t0, sp_w[0][3], sp_w[0][4], sp_w[0][5], AGG);
    k_upd<<<G4, 256, 0, stream>>>(A, AGG,
        sp_w[0][6], sp_w[0][7], sp_w[0][8], sp_w[0][9], Bb, 1);

    // 3. temporal: QKV (Q->A, K->AGG, V->Vb), attn -> Ob, Wo+pre2 -> A, PRE
    k_qkv<<<G4, 256, 0, stream>>>(Bb, wq, wk, wv, bq, bk, bv, A, AGG, Vb);
    k_attn<<<(BB*NN*NHEADS*TT + 255)/256, 256, 0, stream>>>(A, AGG, Vb, Ob);
    k_wo_pre<<<G4, 256, 0, stream>>>(Ob, wo, bo, sp_w[1][0], A, PRE);

    // 4. spatial 2
    hipMemsetAsync(AGG, 0, BUF*sizeof(float), stream);
    k_msg<<<BT*(EE/64), 64, 0, stream>>>(PRE, ssrc, stgt,
        sp_w[1][1], w2t1, sp_w[1][3], sp_w[1][4], sp_w[1][5], AGG);
    k_upd<<<G4, 256, 0, stream>>>(A, AGG,
        sp_w[1][6], sp_w[1][7], sp_w[1][8], sp_w[1][9], Bb, 1);

    // 5. conv + MLP head
    k_zbuild<<<(BB*NN*64 + 255)/256, 256, 0, stream>>>(Bb, x, conv_w, conv_b, Z);
    k_headmlp<<<(BB*HORZ*NN)/16, 256, 0, stream>>>(Z,
        mlp_w1, mlp_b1, mlp_w2, mlp_b2, out);
}

// Round 8
// 665.929 us; speedup vs baseline: 1.1376x; 1.1090x over previous
//
#include <hip/hip_runtime.h>
#include <math.h>

#define BB 4
#define TT 12
#define NN 2000
#define CC 8
#define HH 64
#define EE 32000
#define NHEADS 8
#define HD 8
#define HORZ 12
#define BT (BB*TT)        // 48
#define RR (BT*NN)        // 96000 rows of H=64

using bf16x8 = __attribute__((ext_vector_type(8))) __bf16;
using f16x8  = __attribute__((ext_vector_type(8))) _Float16;
using f16x4  = __attribute__((ext_vector_type(4))) _Float16;
using f32x4  = __attribute__((ext_vector_type(4))) float;

__device__ __forceinline__ float sigmoidf_(float x){ return 1.0f/(1.0f+__expf(-x)); }
__device__ __forceinline__ float siluf_(float x){ return x/(1.0f+__expf(-x)); }

// ================= CSR build (edges sorted by tgt) =================
__global__ void k_hist(const int* __restrict__ eidx, int* __restrict__ cnt) {
    int e = blockIdx.x*blockDim.x + threadIdx.x;
    if (e < EE) atomicAdd(&cnt[eidx[EE + e]], 1);
}

__global__ __launch_bounds__(256) void k_scan(const int* __restrict__ cnt,
                                              int* __restrict__ ofs_work) {
    __shared__ int part[256];
    int tid = threadIdx.x;
    int local[8]; int s = 0;
    #pragma unroll
    for (int k = 0; k < 8; ++k) {
        int idx = tid*8 + k;
        int v = (idx < NN) ? cnt[idx] : 0;
        local[k] = s; s += v;
    }
    part[tid] = s; __syncthreads();
    for (int off = 1; off < 256; off <<= 1) {
        int v = part[tid];
        int u = (tid >= off) ? part[tid-off] : 0;
        __syncthreads();
        part[tid] = v + u;
        __syncthreads();
    }
    int excl = part[tid] - s;
    #pragma unroll
    for (int k = 0; k < 8; ++k) {
        int idx = tid*8 + k;
        if (idx < NN) ofs_work[idx] = excl + local[k];
    }
}

__global__ void k_scatter(const int* __restrict__ eidx, int* __restrict__ ofs_work,
                          int* __restrict__ ssrc, int* __restrict__ stgt) {
    int e = blockIdx.x*blockDim.x + threadIdx.x;
    if (e >= EE) return;
    int t = eidx[EE + e];
    int pos = atomicAdd(&ofs_work[t], 1);
    ssrc[pos] = eidx[e];
    stgt[pos] = t;
}

// ========== both W2 -> bf16, transposed to [n][k], single launch ==========
__global__ void k_w2prep(const float* __restrict__ w2a, const float* __restrict__ w2b,
                         __bf16* __restrict__ w2ta, __bf16* __restrict__ w2tb) {
    int i = blockIdx.x*blockDim.x + threadIdx.x;  // 4096
    if (i >= 4096) return;
    if (i < 2048) { int n = i >> 5, k = i & 31; w2ta[i] = (__bf16)w2a[k*64 + n]; }
    else { int ii = i - 2048; int n = ii >> 5, k = ii & 31; w2tb[ii] = (__bf16)w2b[k*64 + n]; }
}

// ---------------- up-projection (4 rows/wave) ----------------
__global__ void k_up(const float* __restrict__ x, const float* __restrict__ w,
                     const float* __restrict__ b, float* __restrict__ h) {
    int gid = blockIdx.x*blockDim.x + threadIdx.x;
    int wv_ = gid >> 6; int j = gid & 63;
    int r0 = wv_*4;
    if (r0 >= RR) return;
    r0 = __builtin_amdgcn_readfirstlane(r0);
    const float* xr = x + (size_t)r0*CC;
    float bj = b[j];
    float a0=bj,a1=bj,a2=bj,a3=bj;
    #pragma unroll
    for (int c = 0; c < CC; ++c) {
        float wc = w[c*HH + j];
        a0 += xr[c]*wc; a1 += xr[CC+c]*wc; a2 += xr[2*CC+c]*wc; a3 += xr[3*CC+c]*wc;
    }
    h[(size_t)r0*HH + j]        = fmaxf(a0, 0.f);
    h[(size_t)r0*HH + HH + j]   = fmaxf(a1, 0.f);
    h[(size_t)r0*HH + 2*HH + j] = fmaxf(a2, 0.f);
    h[(size_t)r0*HH + 3*HH + j] = fmaxf(a3, 0.f);
}

// ========== per-node precompute of first msg-MLP layer (f16 out) ======
__global__ void k_pre(const float* __restrict__ h, const float* __restrict__ w1,
                      _Float16* __restrict__ preB) {
    int gid = blockIdx.x*blockDim.x + threadIdx.x;
    int wv_ = gid >> 6; int j = gid & 63;
    int r0 = wv_*4;
    if (r0 >= RR) return;
    r0 = __builtin_amdgcn_readfirstlane(r0);
    const float* hr = h + (size_t)r0*HH;
    int base = (j < 32) ? j : (2048 + j - 32);
    float a0=0.f,a1=0.f,a2=0.f,a3=0.f;
    #pragma unroll 8
    for (int c = 0; c < 64; ++c) {
        float wc = w1[c*32 + base];
        a0 += hr[c]*wc; a1 += hr[HH+c]*wc; a2 += hr[2*HH+c]*wc; a3 += hr[3*HH+c]*wc;
    }
    preB[(size_t)r0*HH + j]        = (_Float16)a0;
    preB[(size_t)r0*HH + HH + j]   = (_Float16)a1;
    preB[(size_t)r0*HH + 2*HH + j] = (_Float16)a2;
    preB[(size_t)r0*HH + 3*HH + j] = (_Float16)a3;
}

// ========== message MLP + gate + indicator-MFMA segmented aggregation =====
__global__ __launch_bounds__(64) void k_msg(
    const _Float16* __restrict__ preB, const int* __restrict__ ssrc,
    const int* __restrict__ stgt,
    const float* __restrict__ b1,
    const __bf16* __restrict__ w2t, const float* __restrict__ b2,
    const float* __restrict__ gw, const float* __restrict__ gb,
    float* __restrict__ agg)
{
    const int EB = EE/64; // 500
    int eb = blockIdx.x % EB;
    int bt = blockIdx.x / EB;
    int t  = threadIdx.x;
    int l15 = t & 15, quad = t >> 4;

    union __align__(16) SM {
        __bf16   ab[64][40];
        _Float16 bs[8][64][8];
    };
    __shared__ SM sm;
    __shared__ int segTgt[64];

    int e0 = eb*64;
    int my_src = ssrc[e0 + t];
    int my_tgt = stgt[e0 + t];

    int prevt = __shfl(my_tgt, (t + 63) & 63);
    bool bnd = (t == 0) || (prevt != my_tgt);
    unsigned long long bm = __ballot(bnd);
    int seg = __builtin_amdgcn_mbcnt_hi((unsigned)(bm >> 32),
              __builtin_amdgcn_mbcnt_lo((unsigned)bm, 0u));
    int nseg = __popcll(bm);
    if (bnd) segTgt[seg] = my_tgt;

    const _Float16* basep = preB + (size_t)bt*NN*HH;
    const _Float16* rT = basep + (size_t)my_tgt*HH;
    const _Float16* rS = basep + (size_t)my_src*HH + 32;
    f16x8 xi[4], xj[4];
    #pragma unroll
    for (int g4 = 0; g4 < 4; ++g4) {
        xi[g4] = *(const f16x8*)&rT[8*g4];
        xj[g4] = *(const f16x8*)&rS[8*g4];
    }
    #pragma unroll
    for (int g4 = 0; g4 < 4; ++g4) {
        bf16x8 v;
        #pragma unroll
        for (int u = 0; u < 8; ++u) {
            float m = (float)xi[g4][u] + (float)xj[g4][u] + b1[8*g4 + u];
            v[u] = (__bf16)siluf_(m);
        }
        ((bf16x8*)&sm.ab[t][0])[g4] = v;
    }

    bf16x8 bfr[4];
    float b2v[4], gwv[4];
    #pragma unroll
    for (int ni = 0; ni < 4; ++ni) {
        bfr[ni] = *(const bf16x8*)&w2t[(16*ni + l15)*32 + quad*8];
        b2v[ni] = b2[16*ni + l15];
        gwv[ni] = gw[16*ni + l15];
    }
    float gb0 = gb[0];

    __syncthreads();

    f32x4 acc[4][4];
    #pragma unroll
    for (int mi = 0; mi < 4; ++mi) {
        bf16x8 af = *(const bf16x8*)&sm.ab[16*mi + l15][quad*8];
        #pragma unroll
        for (int ni = 0; ni < 4; ++ni) {
            f32x4 z = {0.f, 0.f, 0.f, 0.f};
            acc[mi][ni] = __builtin_amdgcn_mfma_f32_16x16x32_bf16(af, bfr[ni], z, 0, 0, 0);
        }
    }
    __syncthreads();

    #pragma unroll
    for (int mi = 0; mi < 4; ++mi) {
        float sv[4][4];
        #pragma unroll
        for (int ni = 0; ni < 4; ++ni)
            #pragma unroll
            for (int rg = 0; rg < 4; ++rg)
                sv[ni][rg] = siluf_(acc[mi][ni][rg] + b2v[ni]);
        float gg[4];
        #pragma unroll
        for (int rg = 0; rg < 4; ++rg) {
            float p = sv[0][rg]*gwv[0] + sv[1][rg]*gwv[1]
                    + sv[2][rg]*gwv[2] + sv[3][rg]*gwv[3];
            p += __shfl_xor(p, 1); p += __shfl_xor(p, 2);
            p += __shfl_xor(p, 4); p += __shfl_xor(p, 8);
            gg[rg] = sigmoidf_(p + gb0);
        }
        int c  = mi >> 1;
        int qb = 2*(mi & 1) + (quad >> 1);
        int j0 = 4*(quad & 1);
        #pragma unroll
        for (int ni = 0; ni < 4; ++ni) {
            f16x4 pk;
            #pragma unroll
            for (int rg = 0; rg < 4; ++rg) pk[rg] = (_Float16)(sv[ni][rg]*gg[rg]);
            *(f16x4*)&sm.bs[c*4 + ni][16*qb + l15][j0] = pk;
        }
    }
    __syncthreads();

    f16x8 bfrag[2][4];
    #pragma unroll
    for (int c = 0; c < 2; ++c)
        #pragma unroll
        for (int ni = 0; ni < 4; ++ni)
            bfrag[c][ni] = *(const f16x8*)&sm.bs[c*4 + ni][t][0];

    float* ap = agg + (size_t)bt*NN*HH;
    for (int g0 = 0; g0 < nseg; g0 += 16) {
        f16x8 ind[2];
        #pragma unroll
        for (int c = 0; c < 2; ++c) {
            #pragma unroll
            for (int j = 0; j < 8; ++j) {
                int sj = __shfl(seg, 32*c + 8*quad + j);
                ind[c][j] = (sj == g0 + l15) ? (_Float16)1.0f : (_Float16)0.0f;
            }
        }
        f32x4 av[4];
        #pragma unroll
        for (int ni = 0; ni < 4; ++ni) {
            f32x4 z = {0.f, 0.f, 0.f, 0.f};
            av[ni] = __builtin_amdgcn_mfma_f32_16x16x32_f16(ind[0], bfrag[0][ni], z, 0, 0, 0);
            av[ni] = __builtin_amdgcn_mfma_f32_16x16x32_f16(ind[1], bfrag[1][ni], av[ni], 0, 0, 0);
        }
        #pragma unroll
        for (int rg = 0; rg < 4; ++rg) {
            int s = g0 + 4*quad + rg;
            if (s < nseg) {
                int tn = segTgt[s];
                #pragma unroll
                for (int ni = 0; ni < 4; ++ni)
                    atomicAdd(&ap[(size_t)tn*HH + 16*ni + l15], av[ni][rg]);
            }
        }
    }
}

// ---------------- spatial update (4 rows/wave) ----------------
__global__ void k_upd(const float* __restrict__ h, const float* __restrict__ agg,
                      const float* __restrict__ w1, const float* __restrict__ b1,
                      const float* __restrict__ w2, const float* __restrict__ b2,
                      float* __restrict__ out, int do_relu)
{
    int gid = blockIdx.x*blockDim.x + threadIdx.x;
    int wv_ = gid >> 6; int j = gid & 63;
    int r0 = wv_*4;
    if (r0 >= RR) return;
    r0 = __builtin_amdgcn_readfirstlane(r0);
    const float* ar = agg + (size_t)r0*HH;
    const float* hr = h   + (size_t)r0*HH;
    float bj = b1[j];
    float a0=bj,a1=bj,a2=bj,a3=bj;
    #pragma unroll 8
    for (int c = 0; c < 64; ++c) {
        float wv = w1[c*64 + j];
        a0 += ar[c]*wv; a1 += ar[HH+c]*wv; a2 += ar[2*HH+c]*wv; a3 += ar[3*HH+c]*wv;
    }
    #pragma unroll 8
    for (int c = 0; c < 64; ++c) {
        float wv = w1[(64+c)*64 + j];
        a0 += hr[c]*wv; a1 += hr[HH+c]*wv; a2 += hr[2*HH+c]*wv; a3 += hr[3*HH+c]*wv;
    }
    float u0=siluf_(a0), u1=siluf_(a1), u2=siluf_(a2), u3=siluf_(a3);
    float b2j = b2[j];
    float c0=b2j,c1=b2j,c2=b2j,c3=b2j;
    #pragma unroll 8
    for (int k2 = 0; k2 < 64; ++k2) {
        float wv = w2[k2*64 + j];
        c0 += __shfl(u0,k2)*wv; c1 += __shfl(u1,k2)*wv;
        c2 += __shfl(u2,k2)*wv; c3 += __shfl(u3,k2)*wv;
    }
    float o0 = c0 + hr[j],        o1 = c1 + hr[HH+j];
    float o2 = c2 + hr[2*HH+j],   o3 = c3 + hr[3*HH+j];
    if (do_relu) { o0=fmaxf(o0,0.f); o1=fmaxf(o1,0.f); o2=fmaxf(o2,0.f); o3=fmaxf(o3,0.f); }
    out[(size_t)r0*HH + j]        = o0;
    out[(size_t)r0*HH + HH + j]   = o1;
    out[(size_t)r0*HH + 2*HH + j] = o2;
    out[(size_t)r0*HH + 3*HH + j] = o3;
}

// ---------------- fused QKV projection (4 rows/wave) ----------------
__global__ void k_qkv(const float* __restrict__ h,
                      const float* __restrict__ wq, const float* __restrict__ wk,
                      const float* __restrict__ wv,
                      const float* __restrict__ bq, const float* __restrict__ bk,
                      const float* __restrict__ bv,
                      float* __restrict__ q, float* __restrict__ k, float* __restrict__ v)
{
    int gid = blockIdx.x*blockDim.x + threadIdx.x;
    int wv_ = gid >> 6; int j = gid & 63;
    int r0 = wv_*4;
    if (r0 >= RR) return;
    r0 = __builtin_amdgcn_readfirstlane(r0);
    const float* hr = h + (size_t)r0*HH;
    float q0=bq[j],q1=q0,q2=q0,q3=q0;
    float k0=bk[j],k1=k0,k2v=k0,k3=k0;
    float v0=bv[j],v1=v0,v2=v0,v3=v0;
    #pragma unroll 4
    for (int c = 0; c < 64; ++c) {
        float wqc = wq[c*64 + j], wkc = wk[c*64 + j], wvc = wv[c*64 + j];
        float h0 = hr[c], h1 = hr[HH+c], h2 = hr[2*HH+c], h3 = hr[3*HH+c];
        q0 += h0*wqc; q1 += h1*wqc; q2 += h2*wqc; q3 += h3*wqc;
        k0 += h0*wkc; k1 += h1*wkc; k2v += h2*wkc; k3 += h3*wkc;
        v0 += h0*wvc; v1 += h1*wvc; v2 += h2*wvc; v3 += h3*wvc;
    }
    size_t o = (size_t)r0*HH + j;
    q[o]=q0; q[o+HH]=q1; q[o+2*HH]=q2; q[o+3*HH]=q3;
    k[o]=k0; k[o+HH]=k1; k[o+2*HH]=k2v; k[o+3*HH]=k3;
    v[o]=v0; v[o+HH]=v1; v[o+2*HH]=v2; v[o+3*HH]=v3;
}

// ---------------- temporal attention: wave per (b,n), LDS-staged ----------
__global__ __launch_bounds__(64) void k_attn2(
    const float* __restrict__ q, const float* __restrict__ k,
    const float* __restrict__ v, float* __restrict__ o)
{
    __shared__ float Qs[TT][68], Ks[TT][68], Vs[TT][68], Os[TT][68];
    int p = blockIdx.x;            // (b,n), 8000 blocks
    int b = p / NN, n = p % NN;
    int j = threadIdx.x;
    const size_t stride = (size_t)NN*HH;
    const size_t base0  = ((size_t)(b*TT)*NN + n)*HH;

    #pragma unroll
    for (int t = 0; t < TT; ++t) {
        size_t off = base0 + (size_t)t*stride + j;
        Qs[t][j] = q[off];
        Ks[t][j] = k[off];
        Vs[t][j] = v[off];
    }
    __syncthreads();

    #pragma unroll
    for (int half = 0; half < 2; ++half) {
        if (j < 48) {
            int head = half*4 + j/12;
            int s    = j % 12;
            f32x4 qv0 = *(const f32x4*)&Qs[s][head*8];
            f32x4 qv1 = *(const f32x4*)&Qs[s][head*8 + 4];
            float sc[TT]; float mx = -1e30f;
            #pragma unroll
            for (int t = 0; t < TT; ++t) {
                f32x4 k0 = *(const f32x4*)&Ks[t][head*8];
                f32x4 k1 = *(const f32x4*)&Ks[t][head*8 + 4];
                float a = qv0[0]*k0[0] + qv0[1]*k0[1] + qv0[2]*k0[2] + qv0[3]*k0[3]
                        + qv1[0]*k1[0] + qv1[1]*k1[1] + qv1[2]*k1[2] + qv1[3]*k1[3];
                a *= 0.35355339059327373f;
                sc[t] = a; mx = fmaxf(mx, a);
            }
            float sum = 0.f;
            #pragma unroll
            for (int t = 0; t < TT; ++t) { sc[t] = __expf(sc[t]-mx); sum += sc[t]; }
            float inv = 1.0f/sum;
            f32x4 o0 = {0.f,0.f,0.f,0.f}, o1 = {0.f,0.f,0.f,0.f};
            #pragma unroll
            for (int t = 0; t < TT; ++t) {
                float a = sc[t]*inv;
                f32x4 v0 = *(const f32x4*)&Vs[t][head*8];
                f32x4 v1 = *(const f32x4*)&Vs[t][head*8 + 4];
                o0[0]+=a*v0[0]; o0[1]+=a*v0[1]; o0[2]+=a*v0[2]; o0[3]+=a*v0[3];
                o1[0]+=a*v1[0]; o1[1]+=a*v1[1]; o1[2]+=a*v1[2]; o1[3]+=a*v1[3];
            }
            *(f32x4*)&Os[s][head*8]     = o0;
            *(f32x4*)&Os[s][head*8 + 4] = o1;
        }
    }
    __syncthreads();

    #pragma unroll
    for (int t = 0; t < TT; ++t)
        o[base0 + (size_t)t*stride + j] = Os[t][j];
}

// ---------------- 64x64 row-GEMM (4 rows/wave) ----------------
__global__ void k_rowgemm64(const float* __restrict__ in, const float* __restrict__ w,
                            const float* __restrict__ b, float* __restrict__ out)
{
    int gid = blockIdx.x*blockDim.x + threadIdx.x;
    int wv_ = gid >> 6; int j = gid & 63;
    int r0 = wv_*4;
    if (r0 >= RR) return;
    r0 = __builtin_amdgcn_readfirstlane(r0);
    const float* ir = in + (size_t)r0*HH;
    float bj = b[j];
    float a0=bj,a1=bj,a2=bj,a3=bj;
    #pragma unroll 8
    for (int c = 0; c < 64; ++c) {
        float wc = w[c*64 + j];
        a0 += ir[c]*wc; a1 += ir[HH+c]*wc; a2 += ir[2*HH+c]*wc; a3 += ir[3*HH+c]*wc;
    }
    out[(size_t)r0*HH + j]        = a0;
    out[(size_t)r0*HH + HH + j]   = a1;
    out[(size_t)r0*HH + 2*HH + j] = a2;
    out[(size_t)r0*HH + 3*HH + j] = a3;
}

// ---------------- conv head stage 1: z[b,hor,n,0:72] ----------------------
__global__ __launch_bounds__(256) void k_zbuild(
    const float* __restrict__ h, const float* __restrict__ x,
    const float* __restrict__ cw, const float* __restrict__ cb,
    float* __restrict__ z)
{
    int gid = blockIdx.x*blockDim.x + threadIdx.x;
    int p = gid >> 6;
    int j = gid & 63;
    if (p >= BB*NN) return;
    p = __builtin_amdgcn_readfirstlane(p);
    int b = p / NN, n = p % NN;

    float hv[TT];
    #pragma unroll
    for (int t = 0; t < TT; ++t)
        hv[t] = h[((size_t)(b*TT + t)*NN + n)*HH + j];
    float xv[TT];
    if (j < CC) {
        #pragma unroll
        for (int t = 0; t < TT; ++t)
            xv[t] = x[((size_t)(b*TT + t)*NN + n)*CC + j];
    }

    #pragma unroll
    for (int hor = 0; hor < HORZ; ++hor) {
        float cbv = cb[hor];
        float zh = cbv, zx = cbv;
        #pragma unroll
        for (int t = 0; t < TT; ++t) {
            float w = cw[hor*TT + t];
            zh += w*hv[t];
            if (j < CC) zx += w*xv[t];
        }
        size_t row = (size_t)(b*HORZ + hor)*NN + n;
        z[row*72 + j] = zh;
        if (j < CC) z[row*72 + 64 + j] = zx;
    }
}

// ---------------- conv head stage 2: out = relu(z@w1+b1)@w2+b2 ------------
__global__ __launch_bounds__(256) void k_headmlp(
    const float* __restrict__ z,
    const float* __restrict__ w1, const float* __restrict__ b1,
    const float* __restrict__ w2, const float* __restrict__ b2,
    float* __restrict__ out)
{
    __shared__ float U[4][4][65];
    int gid = blockIdx.x*blockDim.x + threadIdx.x;
    int wv_ = gid >> 6; int j = gid & 63;
    int wl = threadIdx.x >> 6;
    int r0 = wv_*4;
    r0 = __builtin_amdgcn_readfirstlane(r0);
    const float* zr = z + (size_t)r0*72;
    float bj = b1[j];
    float a0=bj,a1=bj,a2=bj,a3=bj;
    #pragma unroll 8
    for (int c = 0; c < 72; ++c) {
        float wc = w1[c*64 + j];
        a0 += zr[c]*wc; a1 += zr[72+c]*wc; a2 += zr[144+c]*wc; a3 += zr[216+c]*wc;
    }
    U[wl][0][j] = fmaxf(a0, 0.f);
    U[wl][1][j] = fmaxf(a1, 0.f);
    U[wl][2][j] = fmaxf(a2, 0.f);
    U[wl][3][j] = fmaxf(a3, 0.f);
    __syncthreads();

    if (j < 32) {
        int r = j >> 3, c = j & 7;
        float o = b2[c];
        #pragma unroll 8
        for (int k = 0; k < 64; ++k)
            o += U[wl][r][k] * w2[k*8 + c];
        out[(size_t)(r0 + r)*CC + c] = o;
    }
}

extern "C" void kernel_launch(void* const* d_in, const int* in_sizes, int n_in,
                              void* d_out, int out_size, void* d_ws, size_t ws_size,
                              hipStream_t stream) {
    const float* x    = (const float*)d_in[0];
    const int*   eidx = (const int*)d_in[1];
    const float* up_w = (const float*)d_in[2];
    const float* up_b = (const float*)d_in[3];
    const float* sp_w[2][10];
    for (int p = 0; p < 2; ++p)
        for (int i = 0; i < 10; ++i)
            sp_w[p][i] = (const float*)d_in[4 + p*10 + i];
    const float* wq = (const float*)d_in[24];
    const float* wk = (const float*)d_in[25];
    const float* wv = (const float*)d_in[26];
    const float* wo = (const float*)d_in[27];
    const float* bq = (const float*)d_in[28];
    const float* bk = (const float*)d_in[29];
    const float* bv = (const float*)d_in[30];
    const float* bo = (const float*)d_in[31];
    const float* conv_w = (const float*)d_in[32];
    const float* conv_b = (const float*)d_in[33];
    const float* mlp_w1 = (const float*)d_in[34];
    const float* mlp_b1 = (const float*)d_in[35];
    const float* mlp_w2 = (const float*)d_in[36];
    const float* mlp_b2 = (const float*)d_in[37];
    float* out = (float*)d_out;

    const size_t BUF = (size_t)RR*HH;      // 6,144,000 elements
    float* A    = (float*)d_ws;            // h / Q
    float* Bb   = A   + BUF;               // h2
    float* AGG  = Bb  + BUF;               // agg / K
    float* Vb   = AGG + BUF;               // V
    float* Ob   = Vb  + BUF;               // attn out
    _Float16* PRE = (_Float16*)(Ob + BUF); // first-layer precompute (f16)
    int*   cnt      = (int*)(PRE + BUF);
    int*   ofs_work = cnt + 2048;
    int*   ssrc     = ofs_work + 2048;
    int*   stgt     = ssrc + EE;
    __bf16* w2t0    = (__bf16*)(stgt + EE);
    __bf16* w2t1    = w2t0 + 2048;
    float* Z = AGG;   // z (27.6 MB) overlays AGG+Vb (dead by then)

    const int G4 = RR/16;                  // 6000 blocks of 256 (4 rows/wave)

    // ---- CSR build + weight prep ----
    hipMemsetAsync(cnt, 0, 2048*sizeof(int), stream);
    k_hist<<<(EE+255)/256, 256, 0, stream>>>(eidx, cnt);
    k_w2prep<<<16, 256, 0, stream>>>(sp_w[0][2], sp_w[1][2], w2t0, w2t1);
    k_scan<<<1, 256, 0, stream>>>(cnt, ofs_work);
    k_scatter<<<(EE+255)/256, 256, 0, stream>>>(eidx, ofs_work, ssrc, stgt);

    // 1. up-projection
    k_up<<<G4, 256, 0, stream>>>(x, up_w, up_b, A);

    // 2. spatial 1
    hipMemsetAsync(AGG, 0, BUF*sizeof(float), stream);
    k_pre<<<G4, 256, 0, stream>>>(A, sp_w[0][0], PRE);
    k_msg<<<BT*(EE/64), 64, 0, stream>>>(PRE, ssrc, stgt,
        sp_w[0][1], w2t0, sp_w[0][3], sp_w[0][4], sp_w[0][5], AGG);
    k_upd<<<G4, 256, 0, stream>>>(A, AGG,
        sp_w[0][6], sp_w[0][7], sp_w[0][8], sp_w[0][9], Bb, 1);

    // 3. temporal: QKV (Q->A, K->AGG, V->Vb), attn -> Ob, Wo proj -> A
    k_qkv<<<G4, 256, 0, stream>>>(Bb, wq, wk, wv, bq, bk, bv, A, AGG, Vb);
    k_attn2<<<BB*NN, 64, 0, stream>>>(A, AGG, Vb, Ob);
    k_rowgemm64<<<G4, 256, 0, stream>>>(Ob, wo, bo, A);

    // 4. spatial 2
    hipMemsetAsync(AGG, 0, BUF*sizeof(float), stream);
    k_pre<<<G4, 256, 0, stream>>>(A, sp_w[1][0], PRE);
    k_msg<<<BT*(EE/64), 64, 0, stream>>>(PRE, ssrc, stgt,
        sp_w[1][1], w2t1, sp_w[1][3], sp_w[1][4], sp_w[1][5], AGG);
    k_upd<<<G4, 256, 0, stream>>>(A, AGG,
        sp_w[1][6], sp_w[1][7], sp_w[1][8], sp_w[1][9], Bb, 1);

    // 5. conv + MLP head
    k_zbuild<<<(BB*NN*64 + 255)/256, 256, 0, stream>>>(Bb, x, conv_w, conv_b, Z);
    k_headmlp<<<(BB*HORZ*NN)/16, 256, 0, stream>>>(Z,
        mlp_w1, mlp_b1, mlp_w2, mlp_b2, out);
}

// Round 9
// 502.386 us; speedup vs baseline: 1.5079x; 1.3255x over previous
//
#include <hip/hip_runtime.h>
#include <math.h>

#define BB 4
#define TT 12
#define NN 2000
#define CC 8
#define HH 64
#define EE 32000
#define NHEADS 8
#define HD 8
#define HORZ 12
#define BT (BB*TT)        // 48
#define RR (BT*NN)        // 96000 rows of H=64

using bf16x8 = __attribute__((ext_vector_type(8))) __bf16;
using f16x8  = __attribute__((ext_vector_type(8))) _Float16;
using f16x4  = __attribute__((ext_vector_type(4))) _Float16;
using f32x4  = __attribute__((ext_vector_type(4))) float;

__device__ __forceinline__ float sigmoidf_(float x){ return 1.0f/(1.0f+__expf(-x)); }
__device__ __forceinline__ float siluf_(float x){ return x/(1.0f+__expf(-x)); }

// ================= CSR build (edges sorted by tgt) =================
__global__ void k_hist(const int* __restrict__ eidx, int* __restrict__ cnt) {
    int e = blockIdx.x*blockDim.x + threadIdx.x;
    if (e < EE) atomicAdd(&cnt[eidx[EE + e]], 1);
}

__global__ __launch_bounds__(256) void k_scan(const int* __restrict__ cnt,
                                              int* __restrict__ ofs_work) {
    __shared__ int part[256];
    int tid = threadIdx.x;
    int local[8]; int s = 0;
    #pragma unroll
    for (int k = 0; k < 8; ++k) {
        int idx = tid*8 + k;
        int v = (idx < NN) ? cnt[idx] : 0;
        local[k] = s; s += v;
    }
    part[tid] = s; __syncthreads();
    for (int off = 1; off < 256; off <<= 1) {
        int v = part[tid];
        int u = (tid >= off) ? part[tid-off] : 0;
        __syncthreads();
        part[tid] = v + u;
        __syncthreads();
    }
    int excl = part[tid] - s;
    #pragma unroll
    for (int k = 0; k < 8; ++k) {
        int idx = tid*8 + k;
        if (idx < NN) ofs_work[idx] = excl + local[k];
    }
}

__global__ void k_scatter(const int* __restrict__ eidx, int* __restrict__ ofs_work,
                          int* __restrict__ ssrc, int* __restrict__ stgt) {
    int e = blockIdx.x*blockDim.x + threadIdx.x;
    if (e >= EE) return;
    int t = eidx[EE + e];
    int pos = atomicAdd(&ofs_work[t], 1);
    ssrc[pos] = eidx[e];
    stgt[pos] = t;
}

// ========== one-shot weight prep: transposed [n][k] low-precision copies ==
__global__ void k_wprep(
    const float* __restrict__ mw2_0, const float* __restrict__ mw2_1,  // msg w2 (32x64)
    const float* __restrict__ uw1_0, const float* __restrict__ uw1_1,  // upd w1 (128x64)
    const float* __restrict__ uw2_0, const float* __restrict__ uw2_1,  // upd w2 (64x64)
    const float* __restrict__ wq, const float* __restrict__ wk,
    const float* __restrict__ wv, const float* __restrict__ wo,
    const float* __restrict__ mw1_0, const float* __restrict__ mw1_1,  // msg w1 (128x32)
    __bf16* __restrict__ mw2t0, __bf16* __restrict__ mw2t1,
    _Float16* __restrict__ uw1t0, _Float16* __restrict__ uw1t1,
    _Float16* __restrict__ uw2t0, _Float16* __restrict__ uw2t1,
    _Float16* __restrict__ qkvt, _Float16* __restrict__ wot,
    _Float16* __restrict__ mw1t0, _Float16* __restrict__ mw1t1)
{
    int i = blockIdx.x*blockDim.x + threadIdx.x;
    if (i < 2048) {
        int n = i >> 5, k = i & 31;
        mw2t0[i] = (__bf16)mw2_0[k*64 + n];
        mw2t1[i] = (__bf16)mw2_1[k*64 + n];
        return;
    }
    i -= 2048;
    if (i < 8192) {
        int n = i >> 7, k = i & 127;
        uw1t0[i] = (_Float16)uw1_0[k*64 + n];
        uw1t1[i] = (_Float16)uw1_1[k*64 + n];
        return;
    }
    i -= 8192;
    if (i < 4096) {
        int n = i >> 6, k = i & 63;
        uw2t0[i] = (_Float16)uw2_0[k*64 + n];
        uw2t1[i] = (_Float16)uw2_1[k*64 + n];
        wot[i]   = (_Float16)wo[k*64 + n];
        qkvt[i]        = (_Float16)wq[k*64 + n];
        qkvt[4096 + i] = (_Float16)wk[k*64 + n];
        qkvt[8192 + i] = (_Float16)wv[k*64 + n];
        // factored msg layer-1: preB col n<32 -> W1_top[:, n], n>=32 -> W1_bot[:, n-32]
        mw1t0[i] = (_Float16)((n < 32) ? mw1_0[k*32 + n] : mw1_0[(64 + k)*32 + n - 32]);
        mw1t1[i] = (_Float16)((n < 32) ? mw1_1[k*32 + n] : mw1_1[(64 + k)*32 + n - 32]);
    }
}

// ---------------- up-projection (4 rows/wave, VALU — C=8 is tiny) --------
__global__ void k_up(const float* __restrict__ x, const float* __restrict__ w,
                     const float* __restrict__ b, float* __restrict__ h) {
    int gid = blockIdx.x*blockDim.x + threadIdx.x;
    int wv_ = gid >> 6; int j = gid & 63;
    int r0 = wv_*4;
    if (r0 >= RR) return;
    r0 = __builtin_amdgcn_readfirstlane(r0);
    const float* xr = x + (size_t)r0*CC;
    float bj = b[j];
    float a0=bj,a1=bj,a2=bj,a3=bj;
    #pragma unroll
    for (int c = 0; c < CC; ++c) {
        float wc = w[c*HH + j];
        a0 += xr[c]*wc; a1 += xr[CC+c]*wc; a2 += xr[2*CC+c]*wc; a3 += xr[3*CC+c]*wc;
    }
    h[(size_t)r0*HH + j]        = fmaxf(a0, 0.f);
    h[(size_t)r0*HH + HH + j]   = fmaxf(a1, 0.f);
    h[(size_t)r0*HH + 2*HH + j] = fmaxf(a2, 0.f);
    h[(size_t)r0*HH + 3*HH + j] = fmaxf(a3, 0.f);
}

// ====== MFMA helpers: 32-row tile per wave, A direct from global f32 ======
__device__ __forceinline__ f16x8 load_a_f16(const float* __restrict__ p) {
    f32x4 lo = *(const f32x4*)p, hi = *(const f32x4*)(p + 4);
    f16x8 v;
    #pragma unroll
    for (int u = 0; u < 4; ++u) { v[u] = (_Float16)lo[u]; v[4+u] = (_Float16)hi[u]; }
    return v;
}

// ---------------- MFMA pre: preB = h @ mw1t  (K=64, f16 out) -------------
__global__ __launch_bounds__(64) void k_prem(
    const float* __restrict__ h, const _Float16* __restrict__ mw1t,
    _Float16* __restrict__ preB)
{
    int t = threadIdx.x; int l15 = t & 15, quad = t >> 4;
    size_t R0 = (size_t)blockIdx.x*32;
    f32x4 acc[2][4];
    #pragma unroll
    for (int mi = 0; mi < 2; ++mi)
        #pragma unroll
        for (int ni = 0; ni < 4; ++ni) acc[mi][ni] = (f32x4){0.f,0.f,0.f,0.f};
    #pragma unroll
    for (int kc = 0; kc < 2; ++kc) {
        f16x8 a[2];
        #pragma unroll
        for (int mi = 0; mi < 2; ++mi)
            a[mi] = load_a_f16(h + (R0 + 16*mi + l15)*HH + kc*32 + quad*8);
        #pragma unroll
        for (int ni = 0; ni < 4; ++ni) {
            f16x8 b = *(const f16x8*)&mw1t[(16*ni + l15)*64 + kc*32 + quad*8];
            #pragma unroll
            for (int mi = 0; mi < 2; ++mi)
                acc[mi][ni] = __builtin_amdgcn_mfma_f32_16x16x32_f16(a[mi], b, acc[mi][ni], 0,0,0);
        }
    }
    #pragma unroll
    for (int mi = 0; mi < 2; ++mi)
        #pragma unroll
        for (int ni = 0; ni < 4; ++ni) {
            int col = 16*ni + l15;
            #pragma unroll
            for (int rg = 0; rg < 4; ++rg) {
                int row = 16*mi + 4*quad + rg;
                preB[(R0 + row)*HH + col] = (_Float16)acc[mi][ni][rg];
            }
        }
}

// ---------------- MFMA QKV: 3 projections sharing A-frags ----------------
__global__ __launch_bounds__(64) void k_qkvm(
    const float* __restrict__ h, const _Float16* __restrict__ qkvt,
    const float* __restrict__ bq, const float* __restrict__ bk,
    const float* __restrict__ bv,
    float* __restrict__ q, float* __restrict__ k, float* __restrict__ v)
{
    int t = threadIdx.x; int l15 = t & 15, quad = t >> 4;
    size_t R0 = (size_t)blockIdx.x*32;
    f16x8 a[2][2];
    #pragma unroll
    for (int kc = 0; kc < 2; ++kc)
        #pragma unroll
        for (int mi = 0; mi < 2; ++mi)
            a[kc][mi] = load_a_f16(h + (R0 + 16*mi + l15)*HH + kc*32 + quad*8);

    const float* bias[3] = {bq, bk, bv};
    float* outp[3] = {q, k, v};
    #pragma unroll
    for (int o = 0; o < 3; ++o) {
        f32x4 acc[2][4];
        #pragma unroll
        for (int mi = 0; mi < 2; ++mi)
            #pragma unroll
            for (int ni = 0; ni < 4; ++ni) acc[mi][ni] = (f32x4){0.f,0.f,0.f,0.f};
        #pragma unroll
        for (int kc = 0; kc < 2; ++kc)
            #pragma unroll
            for (int ni = 0; ni < 4; ++ni) {
                f16x8 b = *(const f16x8*)&qkvt[o*4096 + (16*ni + l15)*64 + kc*32 + quad*8];
                #pragma unroll
                for (int mi = 0; mi < 2; ++mi)
                    acc[mi][ni] = __builtin_amdgcn_mfma_f32_16x16x32_f16(a[kc][mi], b, acc[mi][ni], 0,0,0);
            }
        #pragma unroll
        for (int mi = 0; mi < 2; ++mi)
            #pragma unroll
            for (int ni = 0; ni < 4; ++ni) {
                int col = 16*ni + l15;
                float bb = bias[o][col];
                #pragma unroll
                for (int rg = 0; rg < 4; ++rg) {
                    int row = 16*mi + 4*quad + rg;
                    outp[o][(R0 + row)*HH + col] = acc[mi][ni][rg] + bb;
                }
            }
    }
}

// ------- MFMA update MLP: out = silu([agg,h]@w1+b1)@w2+b2 + h (relu) -----
__global__ __launch_bounds__(64) void k_updm(
    const float* __restrict__ agg, const float* __restrict__ h,
    const _Float16* __restrict__ w1t, const float* __restrict__ b1,
    const _Float16* __restrict__ w2t, const float* __restrict__ b2,
    float* __restrict__ out, int do_relu)
{
    __shared__ _Float16 uS[32][72];
    int t = threadIdx.x; int l15 = t & 15, quad = t >> 4;
    size_t R0 = (size_t)blockIdx.x*32;

    // layer 1: K=128 ([agg | h])
    f32x4 acc[2][4];
    #pragma unroll
    for (int mi = 0; mi < 2; ++mi)
        #pragma unroll
        for (int ni = 0; ni < 4; ++ni) acc[mi][ni] = (f32x4){0.f,0.f,0.f,0.f};
    #pragma unroll
    for (int kc = 0; kc < 4; ++kc) {
        const float* src = (kc < 2) ? agg : h;
        int colb = (kc & 1)*32 + quad*8;
        f16x8 a[2];
        #pragma unroll
        for (int mi = 0; mi < 2; ++mi)
            a[mi] = load_a_f16(src + (R0 + 16*mi + l15)*HH + colb);
        #pragma unroll
        for (int ni = 0; ni < 4; ++ni) {
            f16x8 b = *(const f16x8*)&w1t[(16*ni + l15)*128 + kc*32 + quad*8];
            #pragma unroll
            for (int mi = 0; mi < 2; ++mi)
                acc[mi][ni] = __builtin_amdgcn_mfma_f32_16x16x32_f16(a[mi], b, acc[mi][ni], 0,0,0);
        }
    }
    // u = silu(acc + b1) -> LDS (C-layout scatter, f16)
    #pragma unroll
    for (int mi = 0; mi < 2; ++mi)
        #pragma unroll
        for (int ni = 0; ni < 4; ++ni) {
            int col = 16*ni + l15;
            float bb = b1[col];
            #pragma unroll
            for (int rg = 0; rg < 4; ++rg)
                uS[16*mi + 4*quad + rg][col] = (_Float16)siluf_(acc[mi][ni][rg] + bb);
        }
    __syncthreads();

    // layer 2: K=64
    f32x4 acc2[2][4];
    #pragma unroll
    for (int mi = 0; mi < 2; ++mi)
        #pragma unroll
        for (int ni = 0; ni < 4; ++ni) acc2[mi][ni] = (f32x4){0.f,0.f,0.f,0.f};
    #pragma unroll
    for (int kc = 0; kc < 2; ++kc) {
        f16x8 a[2];
        #pragma unroll
        for (int mi = 0; mi < 2; ++mi)
            a[mi] = *(const f16x8*)&uS[16*mi + l15][kc*32 + quad*8];
        #pragma unroll
        for (int ni = 0; ni < 4; ++ni) {
            f16x8 b = *(const f16x8*)&w2t[(16*ni + l15)*64 + kc*32 + quad*8];
            #pragma unroll
            for (int mi = 0; mi < 2; ++mi)
                acc2[mi][ni] = __builtin_amdgcn_mfma_f32_16x16x32_f16(a[mi], b, acc2[mi][ni], 0,0,0);
        }
    }
    // epilogue: + b2 + residual h, optional relu
    #pragma unroll
    for (int mi = 0; mi < 2; ++mi)
        #pragma unroll
        for (int ni = 0; ni < 4; ++ni) {
            int col = 16*ni + l15;
            float bb = b2[col];
            #pragma unroll
            for (int rg = 0; rg < 4; ++rg) {
                int row = 16*mi + 4*quad + rg;
                float o = acc2[mi][ni][rg] + bb + h[(R0 + row)*HH + col];
                if (do_relu) o = fmaxf(o, 0.f);
                out[(R0 + row)*HH + col] = o;
            }
        }
}

// ------- MFMA Wo projection + fused sp2 msg-layer-1 precompute -----------
__global__ __launch_bounds__(64) void k_wopre(
    const float* __restrict__ ob, const _Float16* __restrict__ wot,
    const float* __restrict__ bo, const _Float16* __restrict__ mw1t,
    float* __restrict__ aout, _Float16* __restrict__ preB)
{
    __shared__ _Float16 hS[32][72];
    int t = threadIdx.x; int l15 = t & 15, quad = t >> 4;
    size_t R0 = (size_t)blockIdx.x*32;

    f32x4 acc[2][4];
    #pragma unroll
    for (int mi = 0; mi < 2; ++mi)
        #pragma unroll
        for (int ni = 0; ni < 4; ++ni) acc[mi][ni] = (f32x4){0.f,0.f,0.f,0.f};
    #pragma unroll
    for (int kc = 0; kc < 2; ++kc) {
        f16x8 a[2];
        #pragma unroll
        for (int mi = 0; mi < 2; ++mi)
            a[mi] = load_a_f16(ob + (R0 + 16*mi + l15)*HH + kc*32 + quad*8);
        #pragma unroll
        for (int ni = 0; ni < 4; ++ni) {
            f16x8 b = *(const f16x8*)&wot[(16*ni + l15)*64 + kc*32 + quad*8];
            #pragma unroll
            for (int mi = 0; mi < 2; ++mi)
                acc[mi][ni] = __builtin_amdgcn_mfma_f32_16x16x32_f16(a[mi], b, acc[mi][ni], 0,0,0);
        }
    }
    // store f32 result + stage f16 copy for the pre-MFMA
    #pragma unroll
    for (int mi = 0; mi < 2; ++mi)
        #pragma unroll
        for (int ni = 0; ni < 4; ++ni) {
            int col = 16*ni + l15;
            float bb = bo[col];
            #pragma unroll
            for (int rg = 0; rg < 4; ++rg) {
                int row = 16*mi + 4*quad + rg;
                float o = acc[mi][ni][rg] + bb;
                aout[(R0 + row)*HH + col] = o;
                hS[row][col] = (_Float16)o;
            }
        }
    __syncthreads();

    f32x4 acc2[2][4];
    #pragma unroll
    for (int mi = 0; mi < 2; ++mi)
        #pragma unroll
        for (int ni = 0; ni < 4; ++ni) acc2[mi][ni] = (f32x4){0.f,0.f,0.f,0.f};
    #pragma unroll
    for (int kc = 0; kc < 2; ++kc) {
        f16x8 a[2];
        #pragma unroll
        for (int mi = 0; mi < 2; ++mi)
            a[mi] = *(const f16x8*)&hS[16*mi + l15][kc*32 + quad*8];
        #pragma unroll
        for (int ni = 0; ni < 4; ++ni) {
            f16x8 b = *(const f16x8*)&mw1t[(16*ni + l15)*64 + kc*32 + quad*8];
            #pragma unroll
            for (int mi = 0; mi < 2; ++mi)
                acc2[mi][ni] = __builtin_amdgcn_mfma_f32_16x16x32_f16(a[mi], b, acc2[mi][ni], 0,0,0);
        }
    }
    #pragma unroll
    for (int mi = 0; mi < 2; ++mi)
        #pragma unroll
        for (int ni = 0; ni < 4; ++ni) {
            int col = 16*ni + l15;
            #pragma unroll
            for (int rg = 0; rg < 4; ++rg) {
                int row = 16*mi + 4*quad + rg;
                preB[(R0 + row)*HH + col] = (_Float16)acc2[mi][ni][rg];
            }
        }
}

// ========== message MLP + gate + indicator-MFMA segmented aggregation =====
__global__ __launch_bounds__(64) void k_msg(
    const _Float16* __restrict__ preB, const int* __restrict__ ssrc,
    const int* __restrict__ stgt,
    const float* __restrict__ b1,
    const __bf16* __restrict__ w2t, const float* __restrict__ b2,
    const float* __restrict__ gw, const float* __restrict__ gb,
    float* __restrict__ agg)
{
    const int EB = EE/64; // 500
    int eb = blockIdx.x % EB;
    int bt = blockIdx.x / EB;
    int t  = threadIdx.x;
    int l15 = t & 15, quad = t >> 4;

    union __align__(16) SM {
        __bf16   ab[64][40];
        _Float16 bs[8][64][8];
    };
    __shared__ SM sm;
    __shared__ int segTgt[64];

    int e0 = eb*64;
    int my_src = ssrc[e0 + t];
    int my_tgt = stgt[e0 + t];

    int prevt = __shfl(my_tgt, (t + 63) & 63);
    bool bnd = (t == 0) || (prevt != my_tgt);
    unsigned long long bm = __ballot(bnd);
    int seg = __builtin_amdgcn_mbcnt_hi((unsigned)(bm >> 32),
              __builtin_amdgcn_mbcnt_lo((unsigned)bm, 0u));
    int nseg = __popcll(bm);
    if (bnd) segTgt[seg] = my_tgt;

    const _Float16* basep = preB + (size_t)bt*NN*HH;
    const _Float16* rT = basep + (size_t)my_tgt*HH;
    const _Float16* rS = basep + (size_t)my_src*HH + 32;
    f16x8 xi[4], xj[4];
    #pragma unroll
    for (int g4 = 0; g4 < 4; ++g4) {
        xi[g4] = *(const f16x8*)&rT[8*g4];
        xj[g4] = *(const f16x8*)&rS[8*g4];
    }
    #pragma unroll
    for (int g4 = 0; g4 < 4; ++g4) {
        bf16x8 v;
        #pragma unroll
        for (int u = 0; u < 8; ++u) {
            float m = (float)xi[g4][u] + (float)xj[g4][u] + b1[8*g4 + u];
            v[u] = (__bf16)siluf_(m);
        }
        ((bf16x8*)&sm.ab[t][0])[g4] = v;
    }

    bf16x8 bfr[4];
    float b2v[4], gwv[4];
    #pragma unroll
    for (int ni = 0; ni < 4; ++ni) {
        bfr[ni] = *(const bf16x8*)&w2t[(16*ni + l15)*32 + quad*8];
        b2v[ni] = b2[16*ni + l15];
        gwv[ni] = gw[16*ni + l15];
    }
    float gb0 = gb[0];

    __syncthreads();

    f32x4 acc[4][4];
    #pragma unroll
    for (int mi = 0; mi < 4; ++mi) {
        bf16x8 af = *(const bf16x8*)&sm.ab[16*mi + l15][quad*8];
        #pragma unroll
        for (int ni = 0; ni < 4; ++ni) {
            f32x4 z = {0.f, 0.f, 0.f, 0.f};
            acc[mi][ni] = __builtin_amdgcn_mfma_f32_16x16x32_bf16(af, bfr[ni], z, 0, 0, 0);
        }
    }
    __syncthreads();

    #pragma unroll
    for (int mi = 0; mi < 4; ++mi) {
        float sv[4][4];
        #pragma unroll
        for (int ni = 0; ni < 4; ++ni)
            #pragma unroll
            for (int rg = 0; rg < 4; ++rg)
                sv[ni][rg] = siluf_(acc[mi][ni][rg] + b2v[ni]);
        float gg[4];
        #pragma unroll
        for (int rg = 0; rg < 4; ++rg) {
            float p = sv[0][rg]*gwv[0] + sv[1][rg]*gwv[1]
                    + sv[2][rg]*gwv[2] + sv[3][rg]*gwv[3];
            p += __shfl_xor(p, 1); p += __shfl_xor(p, 2);
            p += __shfl_xor(p, 4); p += __shfl_xor(p, 8);
            gg[rg] = sigmoidf_(p + gb0);
        }
        int c  = mi >> 1;
        int qb = 2*(mi & 1) + (quad >> 1);
        int j0 = 4*(quad & 1);
        #pragma unroll
        for (int ni = 0; ni < 4; ++ni) {
            f16x4 pk;
            #pragma unroll
            for (int rg = 0; rg < 4; ++rg) pk[rg] = (_Float16)(sv[ni][rg]*gg[rg]);
            *(f16x4*)&sm.bs[c*4 + ni][16*qb + l15][j0] = pk;
        }
    }
    __syncthreads();

    f16x8 bfrag[2][4];
    #pragma unroll
    for (int c = 0; c < 2; ++c)
        #pragma unroll
        for (int ni = 0; ni < 4; ++ni)
            bfrag[c][ni] = *(const f16x8*)&sm.bs[c*4 + ni][t][0];

    float* ap = agg + (size_t)bt*NN*HH;
    for (int g0 = 0; g0 < nseg; g0 += 16) {
        f16x8 ind[2];
        #pragma unroll
        for (int c = 0; c < 2; ++c) {
            #pragma unroll
            for (int j = 0; j < 8; ++j) {
                int sj = __shfl(seg, 32*c + 8*quad + j);
                ind[c][j] = (sj == g0 + l15) ? (_Float16)1.0f : (_Float16)0.0f;
            }
        }
        f32x4 av[4];
        #pragma unroll
        for (int ni = 0; ni < 4; ++ni) {
            f32x4 z = {0.f, 0.f, 0.f, 0.f};
            av[ni] = __builtin_amdgcn_mfma_f32_16x16x32_f16(ind[0], bfrag[0][ni], z, 0, 0, 0);
            av[ni] = __builtin_amdgcn_mfma_f32_16x16x32_f16(ind[1], bfrag[1][ni], av[ni], 0, 0, 0);
        }
        #pragma unroll
        for (int rg = 0; rg < 4; ++rg) {
            int s = g0 + 4*quad + rg;
            if (s < nseg) {
                int tn = segTgt[s];
                #pragma unroll
                for (int ni = 0; ni < 4; ++ni)
                    atomicAdd(&ap[(size_t)tn*HH + 16*ni + l15], av[ni][rg]);
            }
        }
    }
}

// ---------------- temporal attention: wave per (b,n), LDS-staged ----------
__global__ __launch_bounds__(64) void k_attn2(
    const float* __restrict__ q, const float* __restrict__ k,
    const float* __restrict__ v, float* __restrict__ o)
{
    __shared__ float Qs[TT][68], Ks[TT][68], Vs[TT][68], Os[TT][68];
    int p = blockIdx.x;
    int b = p / NN, n = p % NN;
    int j = threadIdx.x;
    const size_t stride = (size_t)NN*HH;
    const size_t base0  = ((size_t)(b*TT)*NN + n)*HH;

    #pragma unroll
    for (int t = 0; t < TT; ++t) {
        size_t off = base0 + (size_t)t*stride + j;
        Qs[t][j] = q[off];
        Ks[t][j] = k[off];
        Vs[t][j] = v[off];
    }
    __syncthreads();

    #pragma unroll
    for (int half = 0; half < 2; ++half) {
        if (j < 48) {
            int head = half*4 + j/12;
            int s    = j % 12;
            f32x4 qv0 = *(const f32x4*)&Qs[s][head*8];
            f32x4 qv1 = *(const f32x4*)&Qs[s][head*8 + 4];
            float sc[TT]; float mx = -1e30f;
            #pragma unroll
            for (int t = 0; t < TT; ++t) {
                f32x4 k0 = *(const f32x4*)&Ks[t][head*8];
                f32x4 k1 = *(const f32x4*)&Ks[t][head*8 + 4];
                float a = qv0[0]*k0[0] + qv0[1]*k0[1] + qv0[2]*k0[2] + qv0[3]*k0[3]
                        + qv1[0]*k1[0] + qv1[1]*k1[1] + qv1[2]*k1[2] + qv1[3]*k1[3];
                a *= 0.35355339059327373f;
                sc[t] = a; mx = fmaxf(mx, a);
            }
            float sum = 0.f;
            #pragma unroll
            for (int t = 0; t < TT; ++t) { sc[t] = __expf(sc[t]-mx); sum += sc[t]; }
            float inv = 1.0f/sum;
            f32x4 o0 = {0.f,0.f,0.f,0.f}, o1 = {0.f,0.f,0.f,0.f};
            #pragma unroll
            for (int t = 0; t < TT; ++t) {
                float a = sc[t]*inv;
                f32x4 v0 = *(const f32x4*)&Vs[t][head*8];
                f32x4 v1 = *(const f32x4*)&Vs[t][head*8 + 4];
                o0[0]+=a*v0[0]; o0[1]+=a*v0[1]; o0[2]+=a*v0[2]; o0[3]+=a*v0[3];
                o1[0]+=a*v1[0]; o1[1]+=a*v1[1]; o1[2]+=a*v1[2]; o1[3]+=a*v1[3];
            }
            *(f32x4*)&Os[s][head*8]     = o0;
            *(f32x4*)&Os[s][head*8 + 4] = o1;
        }
    }
    __syncthreads();

    #pragma unroll
    for (int t = 0; t < TT; ++t)
        o[base0 + (size_t)t*stride + j] = Os[t][j];
}

// ---------------- conv head stage 1: z[b,hor,n,0:72] ----------------------
__global__ __launch_bounds__(256) void k_zbuild(
    const float* __restrict__ h, const float* __restrict__ x,
    const float* __restrict__ cw, const float* __restrict__ cb,
    float* __restrict__ z)
{
    int gid = blockIdx.x*blockDim.x + threadIdx.x;
    int p = gid >> 6;
    int j = gid & 63;
    if (p >= BB*NN) return;
    p = __builtin_amdgcn_readfirstlane(p);
    int b = p / NN, n = p % NN;

    float hv[TT];
    #pragma unroll
    for (int t = 0; t < TT; ++t)
        hv[t] = h[((size_t)(b*TT + t)*NN + n)*HH + j];
    float xv[TT];
    if (j < CC) {
        #pragma unroll
        for (int t = 0; t < TT; ++t)
            xv[t] = x[((size_t)(b*TT + t)*NN + n)*CC + j];
    }

    #pragma unroll
    for (int hor = 0; hor < HORZ; ++hor) {
        float cbv = cb[hor];
        float zh = cbv, zx = cbv;
        #pragma unroll
        for (int t = 0; t < TT; ++t) {
            float w = cw[hor*TT + t];
            zh += w*hv[t];
            if (j < CC) zx += w*xv[t];
        }
        size_t row = (size_t)(b*HORZ + hor)*NN + n;
        z[row*72 + j] = zh;
        if (j < CC) z[row*72 + 64 + j] = zx;
    }
}

// ---------------- conv head stage 2: out = relu(z@w1+b1)@w2+b2 ------------
__global__ __launch_bounds__(256) void k_headmlp(
    const float* __restrict__ z,
    const float* __restrict__ w1, const float* __restrict__ b1,
    const float* __restrict__ w2, const float* __restrict__ b2,
    float* __restrict__ out)
{
    __shared__ float U[4][4][65];
    int gid = blockIdx.x*blockDim.x + threadIdx.x;
    int wv_ = gid >> 6; int j = gid & 63;
    int wl = threadIdx.x >> 6;
    int r0 = wv_*4;
    r0 = __builtin_amdgcn_readfirstlane(r0);
    const float* zr = z + (size_t)r0*72;
    float bj = b1[j];
    float a0=bj,a1=bj,a2=bj,a3=bj;
    #pragma unroll 8
    for (int c = 0; c < 72; ++c) {
        float wc = w1[c*64 + j];
        a0 += zr[c]*wc; a1 += zr[72+c]*wc; a2 += zr[144+c]*wc; a3 += zr[216+c]*wc;
    }
    U[wl][0][j] = fmaxf(a0, 0.f);
    U[wl][1][j] = fmaxf(a1, 0.f);
    U[wl][2][j] = fmaxf(a2, 0.f);
    U[wl][3][j] = fmaxf(a3, 0.f);
    __syncthreads();

    if (j < 32) {
        int r = j >> 3, c = j & 7;
        float o = b2[c];
        #pragma unroll 8
        for (int k = 0; k < 64; ++k)
            o += U[wl][r][k] * w2[k*8 + c];
        out[(size_t)(r0 + r)*CC + c] = o;
    }
}

extern "C" void kernel_launch(void* const* d_in, const int* in_sizes, int n_in,
                              void* d_out, int out_size, void* d_ws, size_t ws_size,
                              hipStream_t stream) {
    const float* x    = (const float*)d_in[0];
    const int*   eidx = (const int*)d_in[1];
    const float* up_w = (const float*)d_in[2];
    const float* up_b = (const float*)d_in[3];
    const float* sp_w[2][10];
    for (int p = 0; p < 2; ++p)
        for (int i = 0; i < 10; ++i)
            sp_w[p][i] = (const float*)d_in[4 + p*10 + i];
    const float* wq = (const float*)d_in[24];
    const float* wk = (const float*)d_in[25];
    const float* wv = (const float*)d_in[26];
    const float* wo = (const float*)d_in[27];
    const float* bq = (const float*)d_in[28];
    const float* bk = (const float*)d_in[29];
    const float* bv = (const float*)d_in[30];
    const float* bo = (const float*)d_in[31];
    const float* conv_w = (const float*)d_in[32];
    const float* conv_b = (const float*)d_in[33];
    const float* mlp_w1 = (const float*)d_in[34];
    const float* mlp_b1 = (const float*)d_in[35];
    const float* mlp_w2 = (const float*)d_in[36];
    const float* mlp_b2 = (const float*)d_in[37];
    float* out = (float*)d_out;

    const size_t BUF = (size_t)RR*HH;      // 6,144,000 elements
    float* A    = (float*)d_ws;            // h / Q
    float* Bb   = A   + BUF;               // h2
    float* AGG  = Bb  + BUF;               // agg / K
    float* Vb   = AGG + BUF;               // V
    float* Ob   = Vb  + BUF;               // attn out
    _Float16* PRE = (_Float16*)(Ob + BUF); // first-layer precompute (f16)
    int*   cnt      = (int*)(PRE + BUF);
    int*   ofs_work = cnt + 2048;
    int*   ssrc     = ofs_work + 2048;
    int*   stgt     = ssrc + EE;
    __bf16* mw2t0   = (__bf16*)(stgt + EE);   // 2048
    __bf16* mw2t1   = mw2t0 + 2048;           // 2048
    _Float16* uw1t0 = (_Float16*)(mw2t1 + 2048); // 8192
    _Float16* uw1t1 = uw1t0 + 8192;
    _Float16* uw2t0 = uw1t1 + 8192;           // 4096
    _Float16* uw2t1 = uw2t0 + 4096;
    _Float16* qkvt  = uw2t1 + 4096;           // 3*4096
    _Float16* wot   = qkvt + 3*4096;          // 4096
    _Float16* mw1t0 = wot + 4096;             // 4096
    _Float16* mw1t1 = mw1t0 + 4096;
    float* Z = AGG;   // z (27.6 MB) overlays AGG+Vb (dead by then)

    const int G4 = RR/16;   // 6000 blocks of 256 (4 rows/wave)
    const int GT = RR/32;   // 3000 blocks of 64 (32-row MFMA tiles)

    // ---- CSR build + weight prep ----
    hipMemsetAsync(cnt, 0, 2048*sizeof(int), stream);
    k_hist<<<(EE+255)/256, 256, 0, stream>>>(eidx, cnt);
    k_wprep<<<56, 256, 0, stream>>>(
        sp_w[0][2], sp_w[1][2], sp_w[0][6], sp_w[1][6], sp_w[0][8], sp_w[1][8],
        wq, wk, wv, wo, sp_w[0][0], sp_w[1][0],
        mw2t0, mw2t1, uw1t0, uw1t1, uw2t0, uw2t1, qkvt, wot, mw1t0, mw1t1);
    k_scan<<<1, 256, 0, stream>>>(cnt, ofs_work);
    k_scatter<<<(EE+255)/256, 256, 0, stream>>>(eidx, ofs_work, ssrc, stgt);

    // 1. up-projection, then sp1 pre (MFMA)
    k_up<<<G4, 256, 0, stream>>>(x, up_w, up_b, A);
    k_prem<<<GT, 64, 0, stream>>>(A, mw1t0, PRE);

    // 2. spatial 1
    hipMemsetAsync(AGG, 0, BUF*sizeof(float), stream);
    k_msg<<<BT*(EE/64), 64, 0, stream>>>(PRE, ssrc, stgt,
        sp_w[0][1], mw2t0, sp_w[0][3], sp_w[0][4], sp_w[0][5], AGG);
    k_updm<<<GT, 64, 0, stream>>>(AGG, A, uw1t0, sp_w[0][7], uw2t0, sp_w[0][9], Bb, 1);

    // 3. temporal: QKV (Q->A, K->AGG, V->Vb), attn -> Ob, Wo + sp2 pre
    k_qkvm<<<GT, 64, 0, stream>>>(Bb, qkvt, bq, bk, bv, A, AGG, Vb);
    k_attn2<<<BB*NN, 64, 0, stream>>>(A, AGG, Vb, Ob);
    k_wopre<<<GT, 64, 0, stream>>>(Ob, wot, bo, mw1t1, A, PRE);

    // 4. spatial 2
    hipMemsetAsync(AGG, 0, BUF*sizeof(float), stream);
    k_msg<<<BT*(EE/64), 64, 0, stream>>>(PRE, ssrc, stgt,
        sp_w[1][1], mw2t1, sp_w[1][3], sp_w[1][4], sp_w[1][5], AGG);
    k_updm<<<GT, 64, 0, stream>>>(AGG, A, uw1t1, sp_w[1][7], uw2t1, sp_w[1][9], Bb, 1);

    // 5. conv + MLP head
    k_zbuild<<<(BB*NN*64 + 255)/256, 256, 0, stream>>>(Bb, x, conv_w, conv_b, Z);
    k_headmlp<<<(BB*HORZ*NN)/16, 256, 0, stream>>>(Z,
        mlp_w1, mlp_b1, mlp_w2, mlp_b2, out);
}